// Round 2
// baseline (894.511 us; speedup 1.0000x reference)
//
#include <hip/hip_runtime.h>
#include <cstdint>
#include <cstddef>

typedef __bf16 bf16;
typedef __bf16 bf16x4 __attribute__((ext_vector_type(4)));
typedef __bf16 bf16x8 __attribute__((ext_vector_type(8)));
typedef float  fx4    __attribute__((ext_vector_type(4)));

// Problem dims (fixed): B=4, S=2048, D=1024, H=8, E=4, DH=128, K_route=2

// async global->LDS DMA, 16 B per lane; dest = wave-uniform base + lane*16 (m97/m104)
__device__ __forceinline__ void async16(const bf16* g, bf16* l) {
  __builtin_amdgcn_global_load_lds((const __attribute__((address_space(1))) void*)g,
                                   (__attribute__((address_space(3))) void*)l, 16, 0, 0);
}

// DPP row-rotate (within 16-lane rows) — VALU-pipe cross-lane, replaces ds_bpermute-based
// __shfl_xor in reductions (each bpermute ~100+cy LDS latency; DPP ~4cy).
// ROW_ROR:n ctrl = 0x120+n. Rotations by 1,2,4,8 give a full 16-lane reduce.
template <int CTRL>
__device__ __forceinline__ float dppf(float x) {
  return __int_as_float(__builtin_amdgcn_update_dpp(
      0, __float_as_int(x), CTRL, 0xf, 0xf, true));
}

__global__ __launch_bounds__(256) void f32_to_bf16(const float* __restrict__ src,
                                                   bf16* __restrict__ dst, int n) {
  int i = blockIdx.x * 256 + threadIdx.x;
  if (i < n) dst[i] = (bf16)src[i];
}

// wvt[h][dh][e][k] <- v_w[h][e][k][dh]; LDS-tiled 64x64 transpose, coalesced both sides.
// grid (16 ktiles, 2 dhtiles, 32 he)
__global__ __launch_bounds__(256) void make_wvt(const float* __restrict__ v_w,
                                                bf16* __restrict__ wvt) {
  __shared__ float tile[64][65];
  const int he = blockIdx.z, k0 = blockIdx.x * 64, dh0 = blockIdx.y * 64;
  const float* in = v_w + (size_t)he * 1024 * 128;
  #pragma unroll
  for (int j = 0; j < 16; j++) {
    int idx = threadIdx.x + j * 256;
    int r = idx >> 6, c = idx & 63;                 // r=k, c=dh
    tile[r][c] = in[(size_t)(k0 + r) * 128 + dh0 + c];
  }
  __syncthreads();
  const int h = he >> 2, e = he & 3;
  bf16* outp = wvt + ((size_t)(h * 128 + dh0) * 4 + e) * 1024 + k0;
  #pragma unroll
  for (int j = 0; j < 16; j++) {
    int idx = threadIdx.x + j * 256;
    int r = idx >> 6, c = idx & 63;                 // r=dh, c=k
    outp[(size_t)r * 4096 + c] = (bf16)tile[c][r];
  }
}

// wot[d][h][e][dh] <- o_w[h][e][dh][d]; grid (16 dtiles, 2 dhtiles, 32 he)
__global__ __launch_bounds__(256) void make_wot(const float* __restrict__ o_w,
                                                bf16* __restrict__ wot) {
  __shared__ float tile[64][65];
  const int he = blockIdx.z, d0 = blockIdx.x * 64, dh0 = blockIdx.y * 64;
  const float* in = o_w + (size_t)he * 128 * 1024;
  #pragma unroll
  for (int j = 0; j < 16; j++) {
    int idx = threadIdx.x + j * 256;
    int r = idx >> 6, c = idx & 63;                 // r=dh, c=d
    tile[r][c] = in[(size_t)(dh0 + r) * 1024 + d0 + c];
  }
  __syncthreads();
  bf16* outp = wot + (size_t)d0 * 4096 + he * 128 + dh0;
  #pragma unroll
  for (int j = 0; j < 16; j++) {
    int idx = threadIdx.x + j * 256;
    int r = idx >> 6, c = idx & 63;                 // r=d, c=dh
    outp[(size_t)r * 4096 + c] = (bf16)tile[c][r];
  }
}

// ---------------- gating: sigmoid + top-2 of 4 per (token, head), f64 for exact ranking --------
__global__ __launch_bounds__(256) void gating(const float* __restrict__ q_src,
                                              const float* __restrict__ k_src,
                                              const float* __restrict__ sel_v_w,
                                              const float* __restrict__ sel_o_w,
                                              const float* __restrict__ bias_v,
                                              const float* __restrict__ bias_o,
                                              float* __restrict__ gate_v,
                                              float* __restrict__ gate_o,
                                              float* __restrict__ d_out) {
  int m = blockIdx.x, g = blockIdx.y;
  const float* x = g ? q_src : k_src;
  const float* w = g ? sel_o_w : sel_v_w;
  const float* bias = g ? bias_o : bias_v;
  float* gate = g ? gate_o : gate_v;
  float* idxo = d_out + 8388608 + g * 131072;       // v_idx then o_idx, as float values

  __shared__ float xs[1024];
  __shared__ double part_s[32][8];
  __shared__ double sel_s[32];
  int t = threadIdx.x;
  #pragma unroll
  for (int p = 0; p < 4; p++) xs[t + p * 256] = x[(size_t)m * 1024 + t + p * 256];
  __syncthreads();
  int he = t >> 3, pp = t & 7;
  const float* wrow = w + he * 1024;
  double acc = 0.0;
  for (int j = 0; j < 128; j++) { int k = pp + j * 8; acc += (double)xs[k] * (double)wrow[k]; }
  part_s[he][pp] = acc;
  __syncthreads();
  if (t < 32) {
    double tot = 0.0;
    #pragma unroll
    for (int j = 0; j < 8; j++) tot += part_s[t][j];
    sel_s[t] = 1.0 / (1.0 + exp(-tot));
  }
  __syncthreads();
  if (t < 8) {
    double v[4], vbv[4];
    #pragma unroll
    for (int e = 0; e < 4; e++) { v[e] = sel_s[t * 4 + e]; vbv[e] = v[e] + (double)bias[e]; }
    int i0 = 0;
    for (int e = 1; e < 4; e++) if (vbv[e] > vbv[i0]) i0 = e;
    int i1 = -1; double best = -1e300;
    for (int e = 0; e < 4; e++) { if (e == i0) continue; if (vbv[e] > best) { best = vbv[e]; i1 = e; } }
    float* gp = gate + ((size_t)m * 8 + t) * 4;
    #pragma unroll
    for (int e = 0; e < 4; e++) {
      float gv = 0.f;
      if (e == i0) gv = (float)v[i0];
      else if (e == i1) gv = (float)v[i1];
      gp[e] = gv;
    }
    idxo[m * 16 + t * 2 + 0] = (float)i0;
    idxo[m * 16 + t * 2 + 1] = (float)i1;
  }
}

// ---------------- GEMM: C[M x N] = A' @ BT^T, bf16 MFMA 16x16x32, tile 128x128x64 ----------------
// R2: ALL modes DMA-stage A+B via global_load_lds (unpadded stride-64, the 874 TF recipe).
// The expert gate is no longer folded into A (that forced VALU staging with exposed load
// latency). Instead: the gate factor g[m,e] is constant over each K-chunk (e-chunk), and
// per-lane the accumulator row m is fixed -> accumulate each chunk in acc, and at the chunk
// boundary merge accT += g * acc; acc = 0.  (f32 merge is also closer to the reference.)
// MODE 0: plain GEMM (chunk merge disabled); epilogue *scale -> bf16 [b,h,s,dh]
// MODE 1: per-head h=blockIdx.z: A=vsb (re-read per e), CHUNK=1024; epilogue -> vbT [b,h,dh,s]
// MODE 2: A[m, k] = outb[m*1024 + (k>>9)*128 + (k&127)], CHUNK=128; epilogue f32 -> d_out
template <int MODE>
__global__ __launch_bounds__(256) void gemm_moe(const bf16* __restrict__ Abf,
                                                const bf16* __restrict__ BT,
                                                const float* __restrict__ gate,
                                                bf16* __restrict__ Cbf,
                                                float* __restrict__ Cf32,
                                                float scale) {
  constexpr int KDIM = (MODE == 0) ? 1024 : 4096;
  constexpr int SMEMSZ = (MODE == 1) ? 17408 : 16384;   // MODE1 epilogue transpose needs 17408
  __shared__ __align__(16) bf16 smem[SMEMSZ];   // As (128x64) then Bs (128x64)
  bf16* Asp = smem;
  bf16* Bsp = smem + 8192;
  const int t = threadIdx.x;
  const int wave = t >> 6, lane = t & 63;
  const int wr = wave >> 1, wc = wave & 1;
  const int quad = lane >> 4, l16 = lane & 15;
  const int m0 = blockIdx.y * 128;
  const int n0 = blockIdx.x * 128;
  const int h = (MODE == 1) ? blockIdx.z : 0;
  const bf16* BTh = (MODE == 1) ? BT + (size_t)h * 128 * 4096 : BT;

  fx4 acc[4][4] = {};    // MFMA accumulator (per-chunk for modes 1/2)
  fx4 accT[4][4] = {};   // gated total (modes 1/2 only; DCE'd for mode 0)

  const int drow = lane >> 3, dcol = (lane & 7) * 8;   // DMA: 8 rows x 64 cols per wave-pass

  for (int k0 = 0; k0 < KDIM; k0 += 64) {
    // ---- B staging: DMA, 4 passes x (8 rows/wave) ----
    #pragma unroll
    for (int p = 0; p < 4; p++) {
      int rbase = p * 32 + wave * 8;
      async16(BTh + (size_t)(n0 + rbase + drow) * KDIM + k0 + dcol,
              Bsp + rbase * 64 + lane * 8);
    }
    // ---- A staging: DMA (per-mode source address) ----
    #pragma unroll
    for (int p = 0; p < 4; p++) {
      int rbase = p * 32 + wave * 8;
      size_t row = (size_t)(m0 + rbase + drow) * 1024;
      int col = (MODE == 0) ? k0
              : (MODE == 1) ? (k0 & 1023)
                            : (((k0 >> 9) << 7) + (k0 & 127));
      async16(Abf + row + col + dcol, Asp + rbase * 64 + lane * 8);
    }
    __syncthreads();   // drains vmcnt (DMA) + lgkmcnt before fragment reads
    #pragma unroll
    for (int kk = 0; kk < 64; kk += 32) {
      bf16x8 af[4], bfr[4];
      #pragma unroll
      for (int i = 0; i < 4; i++) af[i]  = *(const bf16x8*)(Asp + (wr * 64 + i * 16 + l16) * 64 + kk + quad * 8);
      #pragma unroll
      for (int i = 0; i < 4; i++) bfr[i] = *(const bf16x8*)(Bsp + (wc * 64 + i * 16 + l16) * 64 + kk + quad * 8);
      #pragma unroll
      for (int mi = 0; mi < 4; mi++)
        #pragma unroll
        for (int ni = 0; ni < 4; ni++)
          acc[mi][ni] = __builtin_amdgcn_mfma_f32_16x16x32_bf16(af[mi], bfr[ni], acc[mi][ni], 0, 0, 0);
    }
    // ---- chunk-boundary gate merge (modes 1/2) ----
    if constexpr (MODE != 0) {
      constexpr int CHUNK = (MODE == 1) ? 1024 : 128;
      if (((k0 + 64) & (CHUNK - 1)) == 0) {
        const int e  = (MODE == 1) ? (k0 >> 10) : ((k0 >> 7) & 3);
        const int hh = (MODE == 1) ? h : (k0 >> 9);
        #pragma unroll
        for (int mi = 0; mi < 4; mi++)
          #pragma unroll
          for (int r = 0; r < 4; r++) {
            int m = m0 + wr * 64 + mi * 16 + quad * 4 + r;
            float gv = gate[((size_t)m * 8 + hh) * 4 + e];
            #pragma unroll
            for (int ni = 0; ni < 4; ni++)
              accT[mi][ni][r] += gv * acc[mi][ni][r];
          }
        #pragma unroll
        for (int mi = 0; mi < 4; mi++)
          #pragma unroll
          for (int ni = 0; ni < 4; ni++)
            #pragma unroll
            for (int j = 0; j < 4; j++) acc[mi][ni][j] = 0.f;
      }
    }
    __syncthreads();
  }

  if (MODE == 1) {
    // transpose through LDS -> vbT[b,h,dh,s] with coalesced global writes
    #pragma unroll
    for (int mi = 0; mi < 4; mi++)
      #pragma unroll
      for (int ni = 0; ni < 4; ni++) {
        int nl = wc * 64 + ni * 16 + l16;
        int ml = wr * 64 + mi * 16 + quad * 4;
        bf16x4 pk;
        #pragma unroll
        for (int r = 0; r < 4; r++) pk[r] = (bf16)accT[mi][ni][r];
        *(bf16x4*)(smem + nl * 136 + ml) = pk;   // T[n][m], stride 136
      }
    __syncthreads();
    int b = m0 >> 11, s0 = m0 & 2047;
    const int row = t >> 1, base = (t & 1) * 64;
    bf16* dst = Cbf + (((size_t)(b * 8 + h) * 128) + row) * 2048 + s0 + base;
    #pragma unroll
    for (int j = 0; j < 8; j++)
      *(float4*)(dst + j * 8) = *(float4*)(smem + row * 136 + base + j * 8);
    return;
  }

  // epilogue: C/D layout col=lane&15, row=quad*4+reg
  #pragma unroll
  for (int mi = 0; mi < 4; mi++)
    #pragma unroll
    for (int ni = 0; ni < 4; ni++)
      #pragma unroll
      for (int r = 0; r < 4; r++) {
        int m = m0 + wr * 64 + mi * 16 + quad * 4 + r;
        int n = n0 + wc * 64 + ni * 16 + l16;
        float v = ((MODE == 0) ? acc[mi][ni][r] : accT[mi][ni][r]) * scale;
        if (MODE == 0) {
          int b = m >> 11, s = m & 2047, hh = n >> 7, dh = n & 127;
          Cbf[(((size_t)(b * 8 + hh) * 2048 + s) << 7) + dh] = (bf16)v;
        } else {
          Cf32[(size_t)m * 1024 + n] = v;
        }
      }
}

// ---------------- flash attention (causal), per (b,h) x 64-row q-tile ----------------
// R1: double-buffered K/V via global_load_lds DMA, counted vmcnt(8), raw s_barrier,
//     both-sides 16B-chunk XOR swizzle (rule #21).
// R2: softmax reductions moved from __shfl_xor (ds_bpermute, ~100+cy LDS latency each,
//     8 serial steps/row = the dominant per-tile chain at ~1 wave/SIMD) to DPP row_ror
//     rotations (VALU pipe, ~4cy). The 16-lane groups holding one q-row are exactly
//     DPP rows (lanes quad*16..quad*16+15).
__global__ __launch_bounds__(256) void attn_kernel(const bf16* __restrict__ qb,
                                                   const bf16* __restrict__ kb,
                                                   const bf16* __restrict__ vbT,
                                                   bf16* __restrict__ outb) {
  const int qt = 31 - blockIdx.x;   // heavy blocks dispatch first
  const int bh = blockIdx.y;
  const int b = bh >> 3, h = bh & 7;
  __shared__ __align__(16) bf16 Ks[2][64 * 128];    // [kt-buf][k-row * 128 + dh], swizzled
  __shared__ __align__(16) bf16 VTs[2][128 * 64];   // [kt-buf][dh-row * 64 + s], swizzled
  __shared__ __align__(16) bf16 Ps[4][16][72];
  const int t = threadIdx.x, wave = t >> 6, lane = t & 63;
  const int quad = lane >> 4, l16 = lane & 15;
  const bf16* qbase  = qb  + (size_t)bh * 2048 * 128;
  const bf16* kbase  = kb  + (size_t)bh * 2048 * 128;
  const bf16* vtbase = vbT + (size_t)bh * 128 * 2048;

  // one-time Q fragments straight from global (row-strided 16B loads, once per block)
  bf16x8 qf[4];
  #pragma unroll
  for (int dk = 0; dk < 4; dk++)
    qf[dk] = *(const bf16x8*)(qbase + (size_t)(qt * 64 + wave * 16 + l16) * 128 + dk * 32 + quad * 8);

  // stage K/V tile kt into buffer buf: 8 DMAs/thread. LDS dest linear; global source
  // pre-swizzled so that a swizzled READ retrieves logical elements (involution).
  auto stage = [&](int buf, int kt) {
    #pragma unroll
    for (int p = 0; p < 4; p++) {
      int o = p * 4096 + wave * 1024 + lane * 16;       // byte offset in 16 KiB tile
      int kr = o >> 8, kc = o & 255;                     // 256 B rows (128 bf16)
      async16((const bf16*)((const char*)kbase + (size_t)(kt * 64 + kr) * 256 + (kc ^ ((kr & 7) << 4))),
              (bf16*)((char*)&Ks[buf][0] + o));
    }
    #pragma unroll
    for (int p = 0; p < 4; p++) {
      int o = p * 4096 + wave * 1024 + lane * 16;
      int vr = o >> 7, vc = o & 127;                     // 128 B rows (64 bf16)
      async16((const bf16*)((const char*)vtbase + (size_t)vr * 4096 + kt * 128 + (vc ^ ((vr & 7) << 4))),
              (bf16*)((char*)&VTs[buf][0] + o));
    }
  };

  float m_run[4], l_run[4];
  fx4 acc_o[8] = {};
  #pragma unroll
  for (int r = 0; r < 4; r++) { m_run[r] = -1e30f; l_run[r] = 0.f; }

  stage(0, 0);
  int cur = 0;

  for (int kt = 0; kt <= qt; kt++) {
    if (kt < qt) {
      stage(cur ^ 1, kt + 1);                            // prefetch next tile (8 DMAs stay in flight)
      asm volatile("s_waitcnt vmcnt(8)" ::: "memory");   // wait tile kt only
    } else {
      asm volatile("s_waitcnt vmcnt(0)" ::: "memory");   // last tile: full drain
    }
    __builtin_amdgcn_s_barrier();
    asm volatile("" ::: "memory");

    const char* Ksb  = (const char*)&Ks[cur][0];
    const char* VTsb = (const char*)&VTs[cur][0];

    fx4 accs[4] = {};
    __builtin_amdgcn_s_setprio(1);
    #pragma unroll
    for (int ni = 0; ni < 4; ni++)
      #pragma unroll
      for (int dk = 0; dk < 4; dk++) {
        int r = ni * 16 + l16;
        bf16x8 kf = *(const bf16x8*)(Ksb + r * 256 + ((dk * 64 + quad * 16) ^ ((r & 7) << 4)));
        accs[ni] = __builtin_amdgcn_mfma_f32_16x16x32_bf16(qf[dk], kf, accs[ni], 0, 0, 0);
      }
    __builtin_amdgcn_s_setprio(0);

    if (kt == qt) {   // causal mask on the diagonal tile
      #pragma unroll
      for (int ni = 0; ni < 4; ni++)
        #pragma unroll
        for (int r = 0; r < 4; r++) {
          int qr = wave * 16 + quad * 4 + r;
          int kc = ni * 16 + l16;
          if (kc > qr) accs[ni][r] = -1e30f;
        }
    }

    // softmax in exp2 domain (log2e folded into Q scale); DPP row_ror reductions
    #pragma unroll
    for (int r = 0; r < 4; r++) {
      float mx = fmaxf(fmaxf(accs[0][r], accs[1][r]), fmaxf(accs[2][r], accs[3][r]));
      mx = fmaxf(mx, dppf<0x121>(mx));   // row_ror:1
      mx = fmaxf(mx, dppf<0x122>(mx));   // row_ror:2
      mx = fmaxf(mx, dppf<0x124>(mx));   // row_ror:4
      mx = fmaxf(mx, dppf<0x128>(mx));   // row_ror:8
      float m_new = fmaxf(m_run[r], mx);
      float alpha = __builtin_amdgcn_exp2f(m_run[r] - m_new);
      float rs = 0.f;
      #pragma unroll
      for (int ni = 0; ni < 4; ni++) {
        float p = __builtin_amdgcn_exp2f(accs[ni][r] - m_new);
        accs[ni][r] = p; rs += p;
      }
      rs += dppf<0x121>(rs);
      rs += dppf<0x122>(rs);
      rs += dppf<0x124>(rs);
      rs += dppf<0x128>(rs);
      l_run[r] = l_run[r] * alpha + rs;
      m_run[r] = m_new;
      #pragma unroll
      for (int nj = 0; nj < 8; nj++) acc_o[nj][r] *= alpha;
    }

    // P: C-layout -> LDS -> A-layout (per-wave region; DS in-order within a wave)
    #pragma unroll
    for (int ni = 0; ni < 4; ni++)
      #pragma unroll
      for (int r = 0; r < 4; r++)
        Ps[wave][quad * 4 + r][ni * 16 + l16] = (bf16)accs[ni][r];

    __builtin_amdgcn_s_setprio(1);
    #pragma unroll
    for (int step = 0; step < 2; step++) {
      bf16x8 pf = *(const bf16x8*)&Ps[wave][l16][step * 32 + quad * 8];
      #pragma unroll
      for (int nj = 0; nj < 8; nj++) {
        int r = nj * 16 + l16;
        bf16x8 vf = *(const bf16x8*)(VTsb + r * 128 + ((step * 64 + quad * 16) ^ ((r & 7) << 4)));
        acc_o[nj] = __builtin_amdgcn_mfma_f32_16x16x32_bf16(pf, vf, acc_o[nj], 0, 0, 0);
      }
    }
    __builtin_amdgcn_s_setprio(0);

    asm volatile("" ::: "memory");
    __builtin_amdgcn_s_barrier();   // all waves done reading buf[cur] before it is re-staged
    cur ^= 1;
  }

  #pragma unroll
  for (int nj = 0; nj < 8; nj++)
    #pragma unroll
    for (int r = 0; r < 4; r++) {
      int s = qt * 64 + wave * 16 + quad * 4 + r;
      int token = b * 2048 + s;
      float o = acc_o[nj][r] / l_run[r];
      outb[((size_t)token * 8 + h) * 128 + nj * 16 + l16] = (bf16)o;
    }
}

// ---------------- launch ----------------
extern "C" void kernel_launch(void* const* d_in, const int* in_sizes, int n_in,
                              void* d_out, int out_size, void* d_ws, size_t ws_size,
                              hipStream_t stream) {
  const float* q_src  = (const float*)d_in[0];
  const float* k_src  = (const float*)d_in[1];
  const float* v_src  = (const float*)d_in[2];
  const float* wq     = (const float*)d_in[3];
  const float* wk     = (const float*)d_in[4];
  const float* sel_v_w = (const float*)d_in[5];
  const float* sel_o_w = (const float*)d_in[6];
  const float* v_w    = (const float*)d_in[7];
  const float* o_w    = (const float*)d_in[8];
  const float* bias_v = (const float*)d_in[9];
  const float* bias_o = (const float*)d_in[10];
  float* out = (float*)d_out;

  char* ws = (char*)d_ws;
  size_t off = 0;
  auto alloc = [&](size_t bytes) { char* p = ws + off; off += (bytes + 255) & ~(size_t)255; return p; };
  bf16* wqb   = (bf16*)alloc((size_t)1024 * 1024 * 2);
  bf16* wkb   = (bf16*)alloc((size_t)1024 * 1024 * 2);
  bf16* wvt   = (bf16*)alloc((size_t)8 * 128 * 4 * 1024 * 2);
  bf16* wot   = (bf16*)alloc((size_t)1024 * 4096 * 2);
  float* gate_v = (float*)alloc((size_t)8192 * 32 * 4);
  float* gate_o = (float*)alloc((size_t)8192 * 32 * 4);
  bf16* qsb   = (bf16*)alloc((size_t)8192 * 1024 * 2);   // bf16 copies of srcs
  bf16* ksb   = (bf16*)alloc((size_t)8192 * 1024 * 2);
  bf16* vsb   = (bf16*)alloc((size_t)8192 * 1024 * 2);
  bf16* qb    = (bf16*)alloc((size_t)8192 * 1024 * 2);   // [b,h,s,dh]
  bf16* kb    = (bf16*)alloc((size_t)8192 * 1024 * 2);   // [b,h,s,dh]
  bf16* vbT   = (bf16*)alloc((size_t)8192 * 1024 * 2);   // [b,h,dh,s]
  bf16* outb  = (bf16*)alloc((size_t)8192 * 1024 * 2);   // [b,s,h,dh]

  f32_to_bf16<<<4096, 256, 0, stream>>>(wq, wqb, 1024 * 1024);
  f32_to_bf16<<<4096, 256, 0, stream>>>(wk, wkb, 1024 * 1024);
  f32_to_bf16<<<32768, 256, 0, stream>>>(q_src, qsb, 8388608);
  f32_to_bf16<<<32768, 256, 0, stream>>>(k_src, ksb, 8388608);
  f32_to_bf16<<<32768, 256, 0, stream>>>(v_src, vsb, 8388608);
  make_wvt<<<dim3(16, 2, 32), 256, 0, stream>>>(v_w, wvt);
  make_wot<<<dim3(16, 2, 32), 256, 0, stream>>>(o_w, wot);
  gating<<<dim3(8192, 2), 256, 0, stream>>>(q_src, k_src, sel_v_w, sel_o_w,
                                            bias_v, bias_o, gate_v, gate_o, out);

  const float ssq = 0.29730177875068026f;            // 128^-0.25 (applied to both q and k)
  const float log2e = 1.4426950408889634f;
  gemm_moe<0><<<dim3(8, 64), 256, 0, stream>>>(qsb, wqb, nullptr, qb, nullptr, ssq * log2e);
  gemm_moe<0><<<dim3(8, 64), 256, 0, stream>>>(ksb, wkb, nullptr, kb, nullptr, ssq);
  gemm_moe<1><<<dim3(1, 64, 8), 256, 0, stream>>>(vsb, wvt, gate_v, vbT, nullptr, 1.0f);
  attn_kernel<<<dim3(32, 32), 256, 0, stream>>>(qb, kb, vbT, outb);
  gemm_moe<2><<<dim3(8, 64), 256, 0, stream>>>(outb, wot, gate_o, nullptr, out, 1.0f);
}

// Round 3
// 733.887 us; speedup vs baseline: 1.2189x; 1.2189x over previous
//
#include <hip/hip_runtime.h>
#include <cstdint>
#include <cstddef>

typedef __bf16 bf16;
typedef __bf16 bf16x4 __attribute__((ext_vector_type(4)));
typedef __bf16 bf16x8 __attribute__((ext_vector_type(8)));
typedef float  fx4    __attribute__((ext_vector_type(4)));

// Problem dims (fixed): B=4, S=2048, D=1024, H=8, E=4, DH=128, K_route=2

// async global->LDS DMA, 16 B per lane; dest = wave-uniform base + lane*16 (m97/m104)
__device__ __forceinline__ void async16(const bf16* g, bf16* l) {
  __builtin_amdgcn_global_load_lds((const __attribute__((address_space(1))) void*)g,
                                   (__attribute__((address_space(3))) void*)l, 16, 0, 0);
}

// DPP row-rotate (within 16-lane rows) — VALU-pipe cross-lane reduce (vs ds_bpermute).
template <int CTRL>
__device__ __forceinline__ float dppf(float x) {
  return __int_as_float(__builtin_amdgcn_update_dpp(
      0, __float_as_int(x), CTRL, 0xf, 0xf, true));
}

__global__ __launch_bounds__(256) void f32_to_bf16(const float* __restrict__ src,
                                                   bf16* __restrict__ dst, int n) {
  int i = blockIdx.x * 256 + threadIdx.x;
  if (i < n) dst[i] = (bf16)src[i];
}

// wvt[h][dh][e][k] <- v_w[h][e][k][dh]; LDS-tiled 64x64 transpose, coalesced both sides.
__global__ __launch_bounds__(256) void make_wvt(const float* __restrict__ v_w,
                                                bf16* __restrict__ wvt) {
  __shared__ float tile[64][65];
  const int he = blockIdx.z, k0 = blockIdx.x * 64, dh0 = blockIdx.y * 64;
  const float* in = v_w + (size_t)he * 1024 * 128;
  #pragma unroll
  for (int j = 0; j < 16; j++) {
    int idx = threadIdx.x + j * 256;
    int r = idx >> 6, c = idx & 63;                 // r=k, c=dh
    tile[r][c] = in[(size_t)(k0 + r) * 128 + dh0 + c];
  }
  __syncthreads();
  const int h = he >> 2, e = he & 3;
  bf16* outp = wvt + ((size_t)(h * 128 + dh0) * 4 + e) * 1024 + k0;
  #pragma unroll
  for (int j = 0; j < 16; j++) {
    int idx = threadIdx.x + j * 256;
    int r = idx >> 6, c = idx & 63;                 // r=dh, c=k
    outp[(size_t)r * 4096 + c] = (bf16)tile[c][r];
  }
}

// wot[d][h][e][dh] <- o_w[h][e][dh][d]
__global__ __launch_bounds__(256) void make_wot(const float* __restrict__ o_w,
                                                bf16* __restrict__ wot) {
  __shared__ float tile[64][65];
  const int he = blockIdx.z, d0 = blockIdx.x * 64, dh0 = blockIdx.y * 64;
  const float* in = o_w + (size_t)he * 128 * 1024;
  #pragma unroll
  for (int j = 0; j < 16; j++) {
    int idx = threadIdx.x + j * 256;
    int r = idx >> 6, c = idx & 63;                 // r=dh, c=d
    tile[r][c] = in[(size_t)(dh0 + r) * 1024 + d0 + c];
  }
  __syncthreads();
  bf16* outp = wot + (size_t)d0 * 4096 + he * 128 + dh0;
  #pragma unroll
  for (int j = 0; j < 16; j++) {
    int idx = threadIdx.x + j * 256;
    int r = idx >> 6, c = idx & 63;                 // r=d, c=dh
    outp[(size_t)r * 4096 + c] = (bf16)tile[c][r];
  }
}

// ---------------- gating: sigmoid + top-2 of 4 per (token, head), f64 for exact ranking --------
__global__ __launch_bounds__(256) void gating(const float* __restrict__ q_src,
                                              const float* __restrict__ k_src,
                                              const float* __restrict__ sel_v_w,
                                              const float* __restrict__ sel_o_w,
                                              const float* __restrict__ bias_v,
                                              const float* __restrict__ bias_o,
                                              float* __restrict__ gate_v,
                                              float* __restrict__ gate_o,
                                              float* __restrict__ d_out) {
  int m = blockIdx.x, g = blockIdx.y;
  const float* x = g ? q_src : k_src;
  const float* w = g ? sel_o_w : sel_v_w;
  const float* bias = g ? bias_o : bias_v;
  float* gate = g ? gate_o : gate_v;
  float* idxo = d_out + 8388608 + g * 131072;       // v_idx then o_idx, as float values

  __shared__ float xs[1024];
  __shared__ double part_s[32][8];
  __shared__ double sel_s[32];
  int t = threadIdx.x;
  #pragma unroll
  for (int p = 0; p < 4; p++) xs[t + p * 256] = x[(size_t)m * 1024 + t + p * 256];
  __syncthreads();
  int he = t >> 3, pp = t & 7;
  const float* wrow = w + he * 1024;
  double acc = 0.0;
  for (int j = 0; j < 128; j++) { int k = pp + j * 8; acc += (double)xs[k] * (double)wrow[k]; }
  part_s[he][pp] = acc;
  __syncthreads();
  if (t < 32) {
    double tot = 0.0;
    #pragma unroll
    for (int j = 0; j < 8; j++) tot += part_s[t][j];
    sel_s[t] = 1.0 / (1.0 + exp(-tot));
  }
  __syncthreads();
  if (t < 8) {
    double v[4], vbv[4];
    #pragma unroll
    for (int e = 0; e < 4; e++) { v[e] = sel_s[t * 4 + e]; vbv[e] = v[e] + (double)bias[e]; }
    int i0 = 0;
    for (int e = 1; e < 4; e++) if (vbv[e] > vbv[i0]) i0 = e;
    int i1 = -1; double best = -1e300;
    for (int e = 0; e < 4; e++) { if (e == i0) continue; if (vbv[e] > best) { best = vbv[e]; i1 = e; } }
    float* gp = gate + ((size_t)m * 8 + t) * 4;
    #pragma unroll
    for (int e = 0; e < 4; e++) {
      float gv = 0.f;
      if (e == i0) gv = (float)v[i0];
      else if (e == i1) gv = (float)v[i1];
      gp[e] = gv;
    }
    idxo[m * 16 + t * 2 + 0] = (float)i0;
    idxo[m * 16 + t * 2 + 1] = (float)i1;
  }
}

// expander: Ae[m][(h*4+e)*128+dh] = outb[m][h*128+dh] * gate_o[m][h][e]
// memory-bound, ~80 MB traffic. Removes all gate work from gemm_moe<2>.
__global__ __launch_bounds__(256) void expand_o(const bf16* __restrict__ outb,
                                                const float* __restrict__ gate_o,
                                                bf16* __restrict__ Ae) {
  int idx = blockIdx.x * 256 + threadIdx.x;   // unit = 8 bf16
  int m = idx >> 9;                           // 512 units per row
  int u = idx & 511;
  int he = u >> 4;                            // h*4+e
  int hh = he >> 2, e = he & 3;
  int dh0 = (u & 15) * 8;
  float gv = gate_o[((size_t)m * 8 + hh) * 4 + e];
  bf16x8 v = *(const bf16x8*)(outb + ((size_t)m * 8 + hh) * 128 + dh0);
  #pragma unroll
  for (int j = 0; j < 8; j++) v[j] = (bf16)((float)v[j] * gv);
  *(bf16x8*)(Ae + (size_t)m * 4096 + u * 8) = v;
}

// ---------------- GEMM: C[M x N] = A @ BT^T, bf16 MFMA 16x16x32, tile 128x128x64 ----------------
// R3: 2-phase pipeline (T3-minimum): double-buffered LDS, prefetch next K-tile via
// global_load_lds at iteration top, counted s_waitcnt vmcnt(8) (prefetch gets a full
// iteration to land), raw s_barrier. All modes DMA-stage A+B (unpadded stride-64).
// MODE 0: KDIM=1024, plain; epilogue *scale -> bf16 [b,h,s,dh]
// MODE 1: per-head h=blockIdx.z, KDIM=4096; gate merged at each 1024-chunk boundary
//         (accT += g*acc, 4 merges total); epilogue LDS-transpose -> vbT [b,h,dh,s]
// MODE 2: KDIM=4096, plain (gate pre-applied by expand_o); epilogue f32 -> d_out
template <int MODE>
__global__ __launch_bounds__(256) void gemm_moe(const bf16* __restrict__ Abf,
                                                const bf16* __restrict__ BT,
                                                const float* __restrict__ gate,
                                                bf16* __restrict__ Cbf,
                                                float* __restrict__ Cf32,
                                                float scale) {
  constexpr int KDIM = (MODE == 0) ? 1024 : 4096;
  constexpr int ASTRIDE = (MODE == 2) ? 4096 : 1024;
  __shared__ __align__(16) bf16 smem[32768];   // [2][As 8192 | Bs 8192]
  const int t = threadIdx.x;
  const int wave = t >> 6, lane = t & 63;
  const int wr = wave >> 1, wc = wave & 1;
  const int quad = lane >> 4, l16 = lane & 15;
  const int m0 = blockIdx.y * 128;
  const int n0 = blockIdx.x * 128;
  const int h = (MODE == 1) ? blockIdx.z : 0;
  const bf16* BTh = (MODE == 1) ? BT + (size_t)h * 128 * 4096 : BT;

  fx4 acc[4][4] = {};    // MFMA accumulator (per-chunk for mode 1)
  fx4 accT[4][4] = {};   // gated total (mode 1 only; DCE'd otherwise)

  const int drow = lane >> 3, dcol = (lane & 7) * 8;   // DMA: 8 rows x 64 cols per wave-pass

  auto stage = [&](int buf, int k0) {
    bf16* As = smem + buf * 16384;
    bf16* Bs = As + 8192;
    #pragma unroll
    for (int p = 0; p < 4; p++) {
      int rbase = p * 32 + wave * 8;
      async16(BTh + (size_t)(n0 + rbase + drow) * KDIM + k0 + dcol,
              Bs + rbase * 64 + lane * 8);
    }
    int col = (MODE == 1) ? (k0 & 1023) : k0;
    #pragma unroll
    for (int p = 0; p < 4; p++) {
      int rbase = p * 32 + wave * 8;
      async16(Abf + (size_t)(m0 + rbase + drow) * ASTRIDE + col + dcol,
              As + rbase * 64 + lane * 8);
    }
  };

  stage(0, 0);
  int buf = 0;
  for (int k0 = 0; k0 < KDIM; k0 += 64) {
    if (k0 + 64 < KDIM) {
      stage(buf ^ 1, k0 + 64);                         // prefetch next K-tile
      asm volatile("s_waitcnt vmcnt(8)" ::: "memory"); // wait current tile only
    } else {
      asm volatile("s_waitcnt vmcnt(0)" ::: "memory");
    }
    __builtin_amdgcn_s_barrier();
    asm volatile("" ::: "memory");
    const bf16* As = smem + buf * 16384;
    const bf16* Bs = As + 8192;
    #pragma unroll
    for (int kk = 0; kk < 64; kk += 32) {
      bf16x8 af[4], bfr[4];
      #pragma unroll
      for (int i = 0; i < 4; i++) af[i]  = *(const bf16x8*)(As + (wr * 64 + i * 16 + l16) * 64 + kk + quad * 8);
      #pragma unroll
      for (int i = 0; i < 4; i++) bfr[i] = *(const bf16x8*)(Bs + (wc * 64 + i * 16 + l16) * 64 + kk + quad * 8);
      #pragma unroll
      for (int mi = 0; mi < 4; mi++)
        #pragma unroll
        for (int ni = 0; ni < 4; ni++)
          acc[mi][ni] = __builtin_amdgcn_mfma_f32_16x16x32_bf16(af[mi], bfr[ni], acc[mi][ni], 0, 0, 0);
    }
    if constexpr (MODE == 1) {
      if (((k0 + 64) & 1023) == 0) {     // expert-chunk boundary: 4 merges total
        const int e = k0 >> 10;
        #pragma unroll
        for (int mi = 0; mi < 4; mi++)
          #pragma unroll
          for (int r = 0; r < 4; r++) {
            int m = m0 + wr * 64 + mi * 16 + quad * 4 + r;
            float gv = gate[((size_t)m * 8 + h) * 4 + e];
            #pragma unroll
            for (int ni = 0; ni < 4; ni++)
              accT[mi][ni][r] += gv * acc[mi][ni][r];
          }
        #pragma unroll
        for (int mi = 0; mi < 4; mi++)
          #pragma unroll
          for (int ni = 0; ni < 4; ni++)
            #pragma unroll
            for (int j = 0; j < 4; j++) acc[mi][ni][j] = 0.f;
      }
    }
    asm volatile("" ::: "memory");
    __builtin_amdgcn_s_barrier();   // all waves done reading buf before it is re-staged
    buf ^= 1;
  }

  if (MODE == 1) {
    // transpose through LDS -> vbT[b,h,dh,s] with coalesced global writes
    #pragma unroll
    for (int mi = 0; mi < 4; mi++)
      #pragma unroll
      for (int ni = 0; ni < 4; ni++) {
        int nl = wc * 64 + ni * 16 + l16;
        int ml = wr * 64 + mi * 16 + quad * 4;
        bf16x4 pk;
        #pragma unroll
        for (int r = 0; r < 4; r++) pk[r] = (bf16)accT[mi][ni][r];
        *(bf16x4*)(smem + nl * 136 + ml) = pk;   // T[n][m], stride 136 (needs 17408 <= 32768)
      }
    __syncthreads();
    int b = m0 >> 11, s0 = m0 & 2047;
    const int row = t >> 1, base = (t & 1) * 64;
    bf16* dst = Cbf + (((size_t)(b * 8 + h) * 128) + row) * 2048 + s0 + base;
    #pragma unroll
    for (int j = 0; j < 8; j++)
      *(float4*)(dst + j * 8) = *(float4*)(smem + row * 136 + base + j * 8);
    return;
  }

  // epilogue: C/D layout col=lane&15, row=quad*4+reg
  #pragma unroll
  for (int mi = 0; mi < 4; mi++)
    #pragma unroll
    for (int ni = 0; ni < 4; ni++)
      #pragma unroll
      for (int r = 0; r < 4; r++) {
        int m = m0 + wr * 64 + mi * 16 + quad * 4 + r;
        int n = n0 + wc * 64 + ni * 16 + l16;
        float v = acc[mi][ni][r] * scale;
        if (MODE == 0) {
          int b = m >> 11, s = m & 2047, hh = n >> 7, dh = n & 127;
          Cbf[(((size_t)(b * 8 + hh) * 2048 + s) << 7) + dh] = (bf16)v;
        } else {
          Cf32[(size_t)m * 1024 + n] = v;
        }
      }
}

// ---------------- flash attention (causal) ----------------
// R1: double-buffered K/V via global_load_lds DMA, counted vmcnt(8), raw s_barrier,
//     both-sides 16B-chunk XOR swizzle. R2: DPP row_ror softmax reductions.
// R3: perfect balance + full co-residency: grid (16,32); block x runs q-tiles (31-x)
//     then (x) = exactly 33 KV-iterations every block; 512 blocks = exactly 2/CU.
__global__ __launch_bounds__(256) void attn_kernel(const bf16* __restrict__ qb,
                                                   const bf16* __restrict__ kb,
                                                   const bf16* __restrict__ vbT,
                                                   bf16* __restrict__ outb) {
  const int bh = blockIdx.y;
  const int b = bh >> 3, h = bh & 7;
  __shared__ __align__(16) bf16 Ks[2][64 * 128];    // [buf][k-row * 128 + dh], swizzled
  __shared__ __align__(16) bf16 VTs[2][128 * 64];   // [buf][dh-row * 64 + s], swizzled
  __shared__ __align__(16) bf16 Ps[4][16][72];
  const int t = threadIdx.x, wave = t >> 6, lane = t & 63;
  const int quad = lane >> 4, l16 = lane & 15;
  const bf16* qbase  = qb  + (size_t)bh * 2048 * 128;
  const bf16* kbase  = kb  + (size_t)bh * 2048 * 128;
  const bf16* vtbase = vbT + (size_t)bh * 128 * 2048;

  auto stage = [&](int buf, int kt) {
    #pragma unroll
    for (int p = 0; p < 4; p++) {
      int o = p * 4096 + wave * 1024 + lane * 16;        // byte offset in 16 KiB tile
      int kr = o >> 8, kc = o & 255;                     // 256 B rows (128 bf16)
      async16((const bf16*)((const char*)kbase + (size_t)(kt * 64 + kr) * 256 + (kc ^ ((kr & 7) << 4))),
              (bf16*)((char*)&Ks[buf][0] + o));
    }
    #pragma unroll
    for (int p = 0; p < 4; p++) {
      int o = p * 4096 + wave * 1024 + lane * 16;
      int vr = o >> 7, vc = o & 127;                     // 128 B rows (64 bf16)
      async16((const bf16*)((const char*)vtbase + (size_t)vr * 4096 + kt * 128 + (vc ^ ((vr & 7) << 4))),
              (bf16*)((char*)&VTs[buf][0] + o));
    }
  };

  #pragma unroll 1
  for (int pass = 0; pass < 2; pass++) {
    const int qt = pass ? blockIdx.x : (31 - blockIdx.x);   // heavy tile first

    bf16x8 qf[4];
    #pragma unroll
    for (int dk = 0; dk < 4; dk++)
      qf[dk] = *(const bf16x8*)(qbase + (size_t)(qt * 64 + wave * 16 + l16) * 128 + dk * 32 + quad * 8);

    float m_run[4], l_run[4];
    fx4 acc_o[8] = {};
    #pragma unroll
    for (int r = 0; r < 4; r++) { m_run[r] = -1e30f; l_run[r] = 0.f; }

    stage(0, 0);
    int cur = 0;

    for (int kt = 0; kt <= qt; kt++) {
      if (kt < qt) {
        stage(cur ^ 1, kt + 1);                            // prefetch next tile
        asm volatile("s_waitcnt vmcnt(8)" ::: "memory");   // wait tile kt only
      } else {
        asm volatile("s_waitcnt vmcnt(0)" ::: "memory");
      }
      __builtin_amdgcn_s_barrier();
      asm volatile("" ::: "memory");

      const char* Ksb  = (const char*)&Ks[cur][0];
      const char* VTsb = (const char*)&VTs[cur][0];

      fx4 accs[4] = {};
      __builtin_amdgcn_s_setprio(1);
      #pragma unroll
      for (int ni = 0; ni < 4; ni++)
        #pragma unroll
        for (int dk = 0; dk < 4; dk++) {
          int r = ni * 16 + l16;
          bf16x8 kf = *(const bf16x8*)(Ksb + r * 256 + ((dk * 64 + quad * 16) ^ ((r & 7) << 4)));
          accs[ni] = __builtin_amdgcn_mfma_f32_16x16x32_bf16(qf[dk], kf, accs[ni], 0, 0, 0);
        }
      __builtin_amdgcn_s_setprio(0);

      if (kt == qt) {   // causal mask on the diagonal tile
        #pragma unroll
        for (int ni = 0; ni < 4; ni++)
          #pragma unroll
          for (int r = 0; r < 4; r++) {
            int qr = wave * 16 + quad * 4 + r;
            int kc = ni * 16 + l16;
            if (kc > qr) accs[ni][r] = -1e30f;
          }
      }

      // softmax in exp2 domain (log2e folded into Q scale); DPP row_ror reductions
      #pragma unroll
      for (int r = 0; r < 4; r++) {
        float mx = fmaxf(fmaxf(accs[0][r], accs[1][r]), fmaxf(accs[2][r], accs[3][r]));
        mx = fmaxf(mx, dppf<0x121>(mx));   // row_ror:1
        mx = fmaxf(mx, dppf<0x122>(mx));   // row_ror:2
        mx = fmaxf(mx, dppf<0x124>(mx));   // row_ror:4
        mx = fmaxf(mx, dppf<0x128>(mx));   // row_ror:8
        float m_new = fmaxf(m_run[r], mx);
        float alpha = __builtin_amdgcn_exp2f(m_run[r] - m_new);
        float rs = 0.f;
        #pragma unroll
        for (int ni = 0; ni < 4; ni++) {
          float p = __builtin_amdgcn_exp2f(accs[ni][r] - m_new);
          accs[ni][r] = p; rs += p;
        }
        rs += dppf<0x121>(rs);
        rs += dppf<0x122>(rs);
        rs += dppf<0x124>(rs);
        rs += dppf<0x128>(rs);
        l_run[r] = l_run[r] * alpha + rs;
        m_run[r] = m_new;
        #pragma unroll
        for (int nj = 0; nj < 8; nj++) acc_o[nj][r] *= alpha;
      }

      // P: C-layout -> LDS -> A-layout (per-wave region; DS in-order within a wave)
      #pragma unroll
      for (int ni = 0; ni < 4; ni++)
        #pragma unroll
        for (int r = 0; r < 4; r++)
          Ps[wave][quad * 4 + r][ni * 16 + l16] = (bf16)accs[ni][r];

      __builtin_amdgcn_s_setprio(1);
      #pragma unroll
      for (int step = 0; step < 2; step++) {
        bf16x8 pf = *(const bf16x8*)&Ps[wave][l16][step * 32 + quad * 8];
        #pragma unroll
        for (int nj = 0; nj < 8; nj++) {
          int r = nj * 16 + l16;
          bf16x8 vf = *(const bf16x8*)(VTsb + r * 128 + ((step * 64 + quad * 16) ^ ((r & 7) << 4)));
          acc_o[nj] = __builtin_amdgcn_mfma_f32_16x16x32_bf16(pf, vf, acc_o[nj], 0, 0, 0);
        }
      }
      __builtin_amdgcn_s_setprio(0);

      asm volatile("" ::: "memory");
      __builtin_amdgcn_s_barrier();   // all waves done reading buf[cur] before re-stage
      cur ^= 1;
    }

    #pragma unroll
    for (int nj = 0; nj < 8; nj++)
      #pragma unroll
      for (int r = 0; r < 4; r++) {
        int s = qt * 64 + wave * 16 + quad * 4 + r;
        int token = b * 2048 + s;
        float o = acc_o[nj][r] / l_run[r];
        outb[((size_t)token * 8 + h) * 128 + nj * 16 + l16] = (bf16)o;
      }
  }
}

// ---------------- launch ----------------
extern "C" void kernel_launch(void* const* d_in, const int* in_sizes, int n_in,
                              void* d_out, int out_size, void* d_ws, size_t ws_size,
                              hipStream_t stream) {
  const float* q_src  = (const float*)d_in[0];
  const float* k_src  = (const float*)d_in[1];
  const float* v_src  = (const float*)d_in[2];
  const float* wq     = (const float*)d_in[3];
  const float* wk     = (const float*)d_in[4];
  const float* sel_v_w = (const float*)d_in[5];
  const float* sel_o_w = (const float*)d_in[6];
  const float* v_w    = (const float*)d_in[7];
  const float* o_w    = (const float*)d_in[8];
  const float* bias_v = (const float*)d_in[9];
  const float* bias_o = (const float*)d_in[10];
  float* out = (float*)d_out;

  char* ws = (char*)d_ws;
  size_t off = 0;
  auto alloc = [&](size_t bytes) { char* p = ws + off; off += (bytes + 255) & ~(size_t)255; return p; };
  bf16* wqb   = (bf16*)alloc((size_t)1024 * 1024 * 2);
  bf16* wkb   = (bf16*)alloc((size_t)1024 * 1024 * 2);
  bf16* wvt   = (bf16*)alloc((size_t)8 * 128 * 4 * 1024 * 2);
  bf16* wot   = (bf16*)alloc((size_t)1024 * 4096 * 2);
  float* gate_v = (float*)alloc((size_t)8192 * 32 * 4);
  float* gate_o = (float*)alloc((size_t)8192 * 32 * 4);
  bf16* qsb   = (bf16*)alloc((size_t)8192 * 1024 * 2);   // bf16 copies of srcs
  bf16* ksb   = (bf16*)alloc((size_t)8192 * 1024 * 2);
  bf16* vsb   = (bf16*)alloc((size_t)8192 * 1024 * 2);
  bf16* qb    = (bf16*)alloc((size_t)8192 * 1024 * 2);   // [b,h,s,dh]
  bf16* kb    = (bf16*)alloc((size_t)8192 * 1024 * 2);   // [b,h,s,dh]
  bf16* vbT   = (bf16*)alloc((size_t)8192 * 1024 * 2);   // [b,h,dh,s]
  bf16* outb  = (bf16*)alloc((size_t)8192 * 1024 * 2);   // [b,s,h,dh]
  // Ae (8192x4096 bf16 = 64 MB) overlays qsb..qb, all dead by the time expand_o runs
  bf16* Ae    = qsb;

  f32_to_bf16<<<4096, 256, 0, stream>>>(wq, wqb, 1024 * 1024);
  f32_to_bf16<<<4096, 256, 0, stream>>>(wk, wkb, 1024 * 1024);
  f32_to_bf16<<<32768, 256, 0, stream>>>(q_src, qsb, 8388608);
  f32_to_bf16<<<32768, 256, 0, stream>>>(k_src, ksb, 8388608);
  f32_to_bf16<<<32768, 256, 0, stream>>>(v_src, vsb, 8388608);
  make_wvt<<<dim3(16, 2, 32), 256, 0, stream>>>(v_w, wvt);
  make_wot<<<dim3(16, 2, 32), 256, 0, stream>>>(o_w, wot);
  gating<<<dim3(8192, 2), 256, 0, stream>>>(q_src, k_src, sel_v_w, sel_o_w,
                                            bias_v, bias_o, gate_v, gate_o, out);

  const float ssq = 0.29730177875068026f;            // 128^-0.25 (applied to both q and k)
  const float log2e = 1.4426950408889634f;
  gemm_moe<0><<<dim3(8, 64), 256, 0, stream>>>(qsb, wqb, nullptr, qb, nullptr, ssq * log2e);
  gemm_moe<0><<<dim3(8, 64), 256, 0, stream>>>(ksb, wkb, nullptr, kb, nullptr, ssq);
  gemm_moe<1><<<dim3(1, 64, 8), 256, 0, stream>>>(vsb, wvt, gate_v, vbT, nullptr, 1.0f);
  attn_kernel<<<dim3(16, 32), 256, 0, stream>>>(qb, kb, vbT, outb);
  expand_o<<<16384, 256, 0, stream>>>(outb, gate_o, Ae);
  gemm_moe<2><<<dim3(8, 64), 256, 0, stream>>>(Ae, wot, nullptr, nullptr, out, 1.0f);
}

// Round 4
// 692.799 us; speedup vs baseline: 1.2912x; 1.0593x over previous
//
#include <hip/hip_runtime.h>
#include <cstdint>
#include <cstddef>

typedef __bf16 bf16;
typedef __bf16 bf16x4 __attribute__((ext_vector_type(4)));
typedef __bf16 bf16x8 __attribute__((ext_vector_type(8)));
typedef float  fx4    __attribute__((ext_vector_type(4)));

// Problem dims (fixed): B=4, S=2048, D=1024, H=8, E=4, DH=128, K_route=2

// async global->LDS DMA, 16 B per lane; dest = wave-uniform base + lane*16 (m97/m104)
__device__ __forceinline__ void async16(const bf16* g, bf16* l) {
  __builtin_amdgcn_global_load_lds((const __attribute__((address_space(1))) void*)g,
                                   (__attribute__((address_space(3))) void*)l, 16, 0, 0);
}

// DPP row-rotate (within 16-lane rows) — VALU-pipe cross-lane reduce (vs ds_bpermute).
template <int CTRL>
__device__ __forceinline__ float dppf(float x) {
  return __int_as_float(__builtin_amdgcn_update_dpp(
      0, __float_as_int(x), CTRL, 0xf, 0xf, true));
}

// vectorized f32 -> bf16 (G13: 16B/lane loads), n4 = n/4
__global__ __launch_bounds__(256) void f32_to_bf16(const float4* __restrict__ src,
                                                   bf16x4* __restrict__ dst, int n4) {
  int i = blockIdx.x * 256 + threadIdx.x;
  if (i < n4) {
    float4 v = src[i];
    bf16x4 o;
    o[0] = (bf16)v.x; o[1] = (bf16)v.y; o[2] = (bf16)v.z; o[3] = (bf16)v.w;
    dst[i] = o;
  }
}

// wvt[h][dh][e][k] <- v_w[h][e][k][dh]; LDS-tiled 64x64 transpose, coalesced both sides.
__global__ __launch_bounds__(256) void make_wvt(const float* __restrict__ v_w,
                                                bf16* __restrict__ wvt) {
  __shared__ float tile[64][65];
  const int he = blockIdx.z, k0 = blockIdx.x * 64, dh0 = blockIdx.y * 64;
  const float* in = v_w + (size_t)he * 1024 * 128;
  #pragma unroll
  for (int j = 0; j < 16; j++) {
    int idx = threadIdx.x + j * 256;
    int r = idx >> 6, c = idx & 63;                 // r=k, c=dh
    tile[r][c] = in[(size_t)(k0 + r) * 128 + dh0 + c];
  }
  __syncthreads();
  const int h = he >> 2, e = he & 3;
  bf16* outp = wvt + ((size_t)(h * 128 + dh0) * 4 + e) * 1024 + k0;
  #pragma unroll
  for (int j = 0; j < 16; j++) {
    int idx = threadIdx.x + j * 256;
    int r = idx >> 6, c = idx & 63;                 // r=dh, c=k
    outp[(size_t)r * 4096 + c] = (bf16)tile[c][r];
  }
}

// wot[d][h][e][dh] <- o_w[h][e][dh][d]
__global__ __launch_bounds__(256) void make_wot(const float* __restrict__ o_w,
                                                bf16* __restrict__ wot) {
  __shared__ float tile[64][65];
  const int he = blockIdx.z, d0 = blockIdx.x * 64, dh0 = blockIdx.y * 64;
  const float* in = o_w + (size_t)he * 128 * 1024;
  #pragma unroll
  for (int j = 0; j < 16; j++) {
    int idx = threadIdx.x + j * 256;
    int r = idx >> 6, c = idx & 63;                 // r=dh, c=d
    tile[r][c] = in[(size_t)(dh0 + r) * 1024 + d0 + c];
  }
  __syncthreads();
  bf16* outp = wot + (size_t)d0 * 4096 + he * 128 + dh0;
  #pragma unroll
  for (int j = 0; j < 16; j++) {
    int idx = threadIdx.x + j * 256;
    int r = idx >> 6, c = idx & 63;                 // r=d, c=dh
    outp[(size_t)r * 4096 + c] = (bf16)tile[c][r];
  }
}

// ---------------- gating: sigmoid + top-2 of 4 per (token, head), f64 for exact ranking --------
__global__ __launch_bounds__(256) void gating(const float* __restrict__ q_src,
                                              const float* __restrict__ k_src,
                                              const float* __restrict__ sel_v_w,
                                              const float* __restrict__ sel_o_w,
                                              const float* __restrict__ bias_v,
                                              const float* __restrict__ bias_o,
                                              float* __restrict__ gate_v,
                                              float* __restrict__ gate_o,
                                              float* __restrict__ d_out) {
  int m = blockIdx.x, g = blockIdx.y;
  const float* x = g ? q_src : k_src;
  const float* w = g ? sel_o_w : sel_v_w;
  const float* bias = g ? bias_o : bias_v;
  float* gate = g ? gate_o : gate_v;
  float* idxo = d_out + 8388608 + g * 131072;       // v_idx then o_idx, as float values

  __shared__ float xs[1024];
  __shared__ double part_s[32][8];
  __shared__ double sel_s[32];
  int t = threadIdx.x;
  #pragma unroll
  for (int p = 0; p < 4; p++) xs[t + p * 256] = x[(size_t)m * 1024 + t + p * 256];
  __syncthreads();
  int he = t >> 3, pp = t & 7;
  const float* wrow = w + he * 1024;
  double acc = 0.0;
  for (int j = 0; j < 128; j++) { int k = pp + j * 8; acc += (double)xs[k] * (double)wrow[k]; }
  part_s[he][pp] = acc;
  __syncthreads();
  if (t < 32) {
    double tot = 0.0;
    #pragma unroll
    for (int j = 0; j < 8; j++) tot += part_s[t][j];
    sel_s[t] = 1.0 / (1.0 + exp(-tot));
  }
  __syncthreads();
  if (t < 8) {
    double v[4], vbv[4];
    #pragma unroll
    for (int e = 0; e < 4; e++) { v[e] = sel_s[t * 4 + e]; vbv[e] = v[e] + (double)bias[e]; }
    int i0 = 0;
    for (int e = 1; e < 4; e++) if (vbv[e] > vbv[i0]) i0 = e;
    int i1 = -1; double best = -1e300;
    for (int e = 0; e < 4; e++) { if (e == i0) continue; if (vbv[e] > best) { best = vbv[e]; i1 = e; } }
    float* gp = gate + ((size_t)m * 8 + t) * 4;
    #pragma unroll
    for (int e = 0; e < 4; e++) {
      float gv = 0.f;
      if (e == i0) gv = (float)v[i0];
      else if (e == i1) gv = (float)v[i1];
      gp[e] = gv;
    }
    idxo[m * 16 + t * 2 + 0] = (float)i0;
    idxo[m * 16 + t * 2 + 1] = (float)i1;
  }
}

// expander: Ae[m][(h*4+e)*128+dh] = outb[m][h*128+dh] * gate_o[m][h][e]
// memory-bound, ~80 MB traffic. Removes all gate work from gemm_moe<2>.
__global__ __launch_bounds__(256) void expand_o(const bf16* __restrict__ outb,
                                                const float* __restrict__ gate_o,
                                                bf16* __restrict__ Ae) {
  int idx = blockIdx.x * 256 + threadIdx.x;   // unit = 8 bf16
  int m = idx >> 9;                           // 512 units per row
  int u = idx & 511;
  int he = u >> 4;                            // h*4+e
  int hh = he >> 2, e = he & 3;
  int dh0 = (u & 15) * 8;
  float gv = gate_o[((size_t)m * 8 + hh) * 4 + e];
  bf16x8 v = *(const bf16x8*)(outb + ((size_t)m * 8 + hh) * 128 + dh0);
  #pragma unroll
  for (int j = 0; j < 8; j++) v[j] = (bf16)((float)v[j] * gv);
  *(bf16x8*)(Ae + (size_t)m * 4096 + u * 8) = v;
}

// ---------------- GEMM: C[M x N] = A @ BT^T, bf16 MFMA 16x16x32, tile 128x128x64 ----------------
// R3: 2-phase pipeline: double-buffered LDS, prefetch via global_load_lds, counted vmcnt(8),
//     raw s_barrier.
// R4 (T2): both-sides 16B-chunk XOR swizzle on As AND Bs. Row-major [128][64] bf16 tiles
// have 128 B rows -> unswizzled ds_read_b128 fragment reads are a 16-way bank conflict
// (16 l16-lanes, same byte column, row-stride 128 B; R3 counters: 2.53e7 conflict cycles,
// ~25% of kernel). Involution: DMA dest linear; global source column-chunk ^= (row&7);
// ds_read chunk ((kk>>3)+quad) ^ (row&7).
// MODE 0: KDIM=1024, plain; epilogue *scale -> bf16 [b,h,s,dh]
// MODE 1: per-head h=blockIdx.z, KDIM=4096; gate merged at each 1024-chunk boundary
//         (accT += g*acc, 4 merges total); epilogue LDS-transpose -> vbT [b,h,dh,s]
// MODE 2: KDIM=4096, plain (gate pre-applied by expand_o); epilogue f32 -> d_out
template <int MODE>
__global__ __launch_bounds__(256) void gemm_moe(const bf16* __restrict__ Abf,
                                                const bf16* __restrict__ BT,
                                                const float* __restrict__ gate,
                                                bf16* __restrict__ Cbf,
                                                float* __restrict__ Cf32,
                                                float scale) {
  constexpr int KDIM = (MODE == 0) ? 1024 : 4096;
  constexpr int ASTRIDE = (MODE == 2) ? 4096 : 1024;
  __shared__ __align__(16) bf16 smem[32768];   // [2][As 8192 | Bs 8192]
  const int t = threadIdx.x;
  const int wave = t >> 6, lane = t & 63;
  const int wr = wave >> 1, wc = wave & 1;
  const int quad = lane >> 4, l16 = lane & 15;
  const int m0 = blockIdx.y * 128;
  const int n0 = blockIdx.x * 128;
  const int h = (MODE == 1) ? blockIdx.z : 0;
  const bf16* BTh = (MODE == 1) ? BT + (size_t)h * 128 * 4096 : BT;

  fx4 acc[4][4] = {};    // MFMA accumulator (per-chunk for mode 1)
  fx4 accT[4][4] = {};   // gated total (mode 1 only; DCE'd otherwise)

  const int drow = lane >> 3, dch = lane & 7;   // DMA: 8 rows x 8 chunks (16 B) per pass

  auto stage = [&](int buf, int k0) {
    bf16* As = smem + buf * 16384;
    bf16* Bs = As + 8192;
    #pragma unroll
    for (int p = 0; p < 4; p++) {
      int row = p * 32 + wave * 8 + drow;
      int sc = dch ^ (row & 7);                          // pre-swizzled source chunk
      async16(BTh + (size_t)(n0 + row) * KDIM + k0 + sc * 8,
              Bs + row * 64 + dch * 8);
    }
    int col = (MODE == 1) ? (k0 & 1023) : k0;
    #pragma unroll
    for (int p = 0; p < 4; p++) {
      int row = p * 32 + wave * 8 + drow;
      int sc = dch ^ (row & 7);
      async16(Abf + (size_t)(m0 + row) * ASTRIDE + col + sc * 8,
              As + row * 64 + dch * 8);
    }
  };

  stage(0, 0);
  int buf = 0;
  for (int k0 = 0; k0 < KDIM; k0 += 64) {
    if (k0 + 64 < KDIM) {
      stage(buf ^ 1, k0 + 64);                         // prefetch next K-tile
      asm volatile("s_waitcnt vmcnt(8)" ::: "memory"); // wait current tile only
    } else {
      asm volatile("s_waitcnt vmcnt(0)" ::: "memory");
    }
    __builtin_amdgcn_s_barrier();
    asm volatile("" ::: "memory");
    const bf16* As = smem + buf * 16384;
    const bf16* Bs = As + 8192;
    #pragma unroll
    for (int kk = 0; kk < 64; kk += 32) {
      bf16x8 af[4], bfr[4];
      #pragma unroll
      for (int i = 0; i < 4; i++) {
        int ar = wr * 64 + i * 16 + l16;
        af[i]  = *(const bf16x8*)(As + ar * 64 + ((((kk >> 3) + quad) ^ (ar & 7)) * 8));
      }
      #pragma unroll
      for (int i = 0; i < 4; i++) {
        int br = wc * 64 + i * 16 + l16;
        bfr[i] = *(const bf16x8*)(Bs + br * 64 + ((((kk >> 3) + quad) ^ (br & 7)) * 8));
      }
      #pragma unroll
      for (int mi = 0; mi < 4; mi++)
        #pragma unroll
        for (int ni = 0; ni < 4; ni++)
          acc[mi][ni] = __builtin_amdgcn_mfma_f32_16x16x32_bf16(af[mi], bfr[ni], acc[mi][ni], 0, 0, 0);
    }
    if constexpr (MODE == 1) {
      if (((k0 + 64) & 1023) == 0) {     // expert-chunk boundary: 4 merges total
        const int e = k0 >> 10;
        #pragma unroll
        for (int mi = 0; mi < 4; mi++)
          #pragma unroll
          for (int r = 0; r < 4; r++) {
            int m = m0 + wr * 64 + mi * 16 + quad * 4 + r;
            float gv = gate[((size_t)m * 8 + h) * 4 + e];
            #pragma unroll
            for (int ni = 0; ni < 4; ni++)
              accT[mi][ni][r] += gv * acc[mi][ni][r];
          }
        #pragma unroll
        for (int mi = 0; mi < 4; mi++)
          #pragma unroll
          for (int ni = 0; ni < 4; ni++)
            #pragma unroll
            for (int j = 0; j < 4; j++) acc[mi][ni][j] = 0.f;
      }
    }
    asm volatile("" ::: "memory");
    __builtin_amdgcn_s_barrier();   // all waves done reading buf before it is re-staged
    buf ^= 1;
  }

  if (MODE == 1) {
    // transpose through LDS -> vbT[b,h,dh,s] with coalesced global writes
    #pragma unroll
    for (int mi = 0; mi < 4; mi++)
      #pragma unroll
      for (int ni = 0; ni < 4; ni++) {
        int nl = wc * 64 + ni * 16 + l16;
        int ml = wr * 64 + mi * 16 + quad * 4;
        bf16x4 pk;
        #pragma unroll
        for (int r = 0; r < 4; r++) pk[r] = (bf16)accT[mi][ni][r];
        *(bf16x4*)(smem + nl * 136 + ml) = pk;   // T[n][m], stride 136 (needs 17408 <= 32768)
      }
    __syncthreads();
    int b = m0 >> 11, s0 = m0 & 2047;
    const int row = t >> 1, base = (t & 1) * 64;
    bf16* dst = Cbf + (((size_t)(b * 8 + h) * 128) + row) * 2048 + s0 + base;
    #pragma unroll
    for (int j = 0; j < 8; j++)
      *(float4*)(dst + j * 8) = *(float4*)(smem + row * 136 + base + j * 8);
    return;
  }

  // epilogue: C/D layout col=lane&15, row=quad*4+reg
  #pragma unroll
  for (int mi = 0; mi < 4; mi++)
    #pragma unroll
    for (int ni = 0; ni < 4; ni++)
      #pragma unroll
      for (int r = 0; r < 4; r++) {
        int m = m0 + wr * 64 + mi * 16 + quad * 4 + r;
        int n = n0 + wc * 64 + ni * 16 + l16;
        float v = acc[mi][ni][r] * scale;
        if (MODE == 0) {
          int b = m >> 11, s = m & 2047, hh = n >> 7, dh = n & 127;
          Cbf[(((size_t)(b * 8 + hh) * 2048 + s) << 7) + dh] = (bf16)v;
        } else {
          Cf32[(size_t)m * 1024 + n] = v;
        }
      }
}

// ---------------- flash attention (causal) ----------------
// R1: double-buffered K/V via global_load_lds DMA, counted vmcnt(8), raw s_barrier,
//     both-sides 16B-chunk XOR swizzle. R2: DPP row_ror softmax reductions.
// R3: perfect balance + full co-residency: grid (16,32); block x runs q-tiles (31-x)
//     then (x) = exactly 33 KV-iterations every block; 512 blocks = exactly 2/CU.
__global__ __launch_bounds__(256) void attn_kernel(const bf16* __restrict__ qb,
                                                   const bf16* __restrict__ kb,
                                                   const bf16* __restrict__ vbT,
                                                   bf16* __restrict__ outb) {
  const int bh = blockIdx.y;
  const int b = bh >> 3, h = bh & 7;
  __shared__ __align__(16) bf16 Ks[2][64 * 128];    // [buf][k-row * 128 + dh], swizzled
  __shared__ __align__(16) bf16 VTs[2][128 * 64];   // [buf][dh-row * 64 + s], swizzled
  __shared__ __align__(16) bf16 Ps[4][16][72];
  const int t = threadIdx.x, wave = t >> 6, lane = t & 63;
  const int quad = lane >> 4, l16 = lane & 15;
  const bf16* qbase  = qb  + (size_t)bh * 2048 * 128;
  const bf16* kbase  = kb  + (size_t)bh * 2048 * 128;
  const bf16* vtbase = vbT + (size_t)bh * 128 * 2048;

  auto stage = [&](int buf, int kt) {
    #pragma unroll
    for (int p = 0; p < 4; p++) {
      int o = p * 4096 + wave * 1024 + lane * 16;        // byte offset in 16 KiB tile
      int kr = o >> 8, kc = o & 255;                     // 256 B rows (128 bf16)
      async16((const bf16*)((const char*)kbase + (size_t)(kt * 64 + kr) * 256 + (kc ^ ((kr & 7) << 4))),
              (bf16*)((char*)&Ks[buf][0] + o));
    }
    #pragma unroll
    for (int p = 0; p < 4; p++) {
      int o = p * 4096 + wave * 1024 + lane * 16;
      int vr = o >> 7, vc = o & 127;                     // 128 B rows (64 bf16)
      async16((const bf16*)((const char*)vtbase + (size_t)vr * 4096 + kt * 128 + (vc ^ ((vr & 7) << 4))),
              (bf16*)((char*)&VTs[buf][0] + o));
    }
  };

  #pragma unroll 1
  for (int pass = 0; pass < 2; pass++) {
    const int qt = pass ? blockIdx.x : (31 - blockIdx.x);   // heavy tile first

    bf16x8 qf[4];
    #pragma unroll
    for (int dk = 0; dk < 4; dk++)
      qf[dk] = *(const bf16x8*)(qbase + (size_t)(qt * 64 + wave * 16 + l16) * 128 + dk * 32 + quad * 8);

    float m_run[4], l_run[4];
    fx4 acc_o[8] = {};
    #pragma unroll
    for (int r = 0; r < 4; r++) { m_run[r] = -1e30f; l_run[r] = 0.f; }

    stage(0, 0);
    int cur = 0;

    for (int kt = 0; kt <= qt; kt++) {
      if (kt < qt) {
        stage(cur ^ 1, kt + 1);                            // prefetch next tile
        asm volatile("s_waitcnt vmcnt(8)" ::: "memory");   // wait tile kt only
      } else {
        asm volatile("s_waitcnt vmcnt(0)" ::: "memory");
      }
      __builtin_amdgcn_s_barrier();
      asm volatile("" ::: "memory");

      const char* Ksb  = (const char*)&Ks[cur][0];
      const char* VTsb = (const char*)&VTs[cur][0];

      fx4 accs[4] = {};
      __builtin_amdgcn_s_setprio(1);
      #pragma unroll
      for (int ni = 0; ni < 4; ni++)
        #pragma unroll
        for (int dk = 0; dk < 4; dk++) {
          int r = ni * 16 + l16;
          bf16x8 kf = *(const bf16x8*)(Ksb + r * 256 + ((dk * 64 + quad * 16) ^ ((r & 7) << 4)));
          accs[ni] = __builtin_amdgcn_mfma_f32_16x16x32_bf16(qf[dk], kf, accs[ni], 0, 0, 0);
        }
      __builtin_amdgcn_s_setprio(0);

      if (kt == qt) {   // causal mask on the diagonal tile
        #pragma unroll
        for (int ni = 0; ni < 4; ni++)
          #pragma unroll
          for (int r = 0; r < 4; r++) {
            int qr = wave * 16 + quad * 4 + r;
            int kc = ni * 16 + l16;
            if (kc > qr) accs[ni][r] = -1e30f;
          }
      }

      // softmax in exp2 domain (log2e folded into Q scale); DPP row_ror reductions
      #pragma unroll
      for (int r = 0; r < 4; r++) {
        float mx = fmaxf(fmaxf(accs[0][r], accs[1][r]), fmaxf(accs[2][r], accs[3][r]));
        mx = fmaxf(mx, dppf<0x121>(mx));   // row_ror:1
        mx = fmaxf(mx, dppf<0x122>(mx));   // row_ror:2
        mx = fmaxf(mx, dppf<0x124>(mx));   // row_ror:4
        mx = fmaxf(mx, dppf<0x128>(mx));   // row_ror:8
        float m_new = fmaxf(m_run[r], mx);
        float alpha = __builtin_amdgcn_exp2f(m_run[r] - m_new);
        float rs = 0.f;
        #pragma unroll
        for (int ni = 0; ni < 4; ni++) {
          float p = __builtin_amdgcn_exp2f(accs[ni][r] - m_new);
          accs[ni][r] = p; rs += p;
        }
        rs += dppf<0x121>(rs);
        rs += dppf<0x122>(rs);
        rs += dppf<0x124>(rs);
        rs += dppf<0x128>(rs);
        l_run[r] = l_run[r] * alpha + rs;
        m_run[r] = m_new;
        #pragma unroll
        for (int nj = 0; nj < 8; nj++) acc_o[nj][r] *= alpha;
      }

      // P: C-layout -> LDS -> A-layout (per-wave region; DS in-order within a wave)
      #pragma unroll
      for (int ni = 0; ni < 4; ni++)
        #pragma unroll
        for (int r = 0; r < 4; r++)
          Ps[wave][quad * 4 + r][ni * 16 + l16] = (bf16)accs[ni][r];

      __builtin_amdgcn_s_setprio(1);
      #pragma unroll
      for (int step = 0; step < 2; step++) {
        bf16x8 pf = *(const bf16x8*)&Ps[wave][l16][step * 32 + quad * 8];
        #pragma unroll
        for (int nj = 0; nj < 8; nj++) {
          int r = nj * 16 + l16;
          bf16x8 vf = *(const bf16x8*)(VTsb + r * 128 + ((step * 64 + quad * 16) ^ ((r & 7) << 4)));
          acc_o[nj] = __builtin_amdgcn_mfma_f32_16x16x32_bf16(pf, vf, acc_o[nj], 0, 0, 0);
        }
      }
      __builtin_amdgcn_s_setprio(0);

      asm volatile("" ::: "memory");
      __builtin_amdgcn_s_barrier();   // all waves done reading buf[cur] before re-stage
      cur ^= 1;
    }

    #pragma unroll
    for (int nj = 0; nj < 8; nj++)
      #pragma unroll
      for (int r = 0; r < 4; r++) {
        int s = qt * 64 + wave * 16 + quad * 4 + r;
        int token = b * 2048 + s;
        float o = acc_o[nj][r] / l_run[r];
        outb[((size_t)token * 8 + h) * 128 + nj * 16 + l16] = (bf16)o;
      }
  }
}

// ---------------- launch ----------------
extern "C" void kernel_launch(void* const* d_in, const int* in_sizes, int n_in,
                              void* d_out, int out_size, void* d_ws, size_t ws_size,
                              hipStream_t stream) {
  const float* q_src  = (const float*)d_in[0];
  const float* k_src  = (const float*)d_in[1];
  const float* v_src  = (const float*)d_in[2];
  const float* wq     = (const float*)d_in[3];
  const float* wk     = (const float*)d_in[4];
  const float* sel_v_w = (const float*)d_in[5];
  const float* sel_o_w = (const float*)d_in[6];
  const float* v_w    = (const float*)d_in[7];
  const float* o_w    = (const float*)d_in[8];
  const float* bias_v = (const float*)d_in[9];
  const float* bias_o = (const float*)d_in[10];
  float* out = (float*)d_out;

  char* ws = (char*)d_ws;
  size_t off = 0;
  auto alloc = [&](size_t bytes) { char* p = ws + off; off += (bytes + 255) & ~(size_t)255; return p; };
  bf16* wqb   = (bf16*)alloc((size_t)1024 * 1024 * 2);
  bf16* wkb   = (bf16*)alloc((size_t)1024 * 1024 * 2);
  bf16* wvt   = (bf16*)alloc((size_t)8 * 128 * 4 * 1024 * 2);
  bf16* wot   = (bf16*)alloc((size_t)1024 * 4096 * 2);
  float* gate_v = (float*)alloc((size_t)8192 * 32 * 4);
  float* gate_o = (float*)alloc((size_t)8192 * 32 * 4);
  bf16* qsb   = (bf16*)alloc((size_t)8192 * 1024 * 2);   // bf16 copies of srcs
  bf16* ksb   = (bf16*)alloc((size_t)8192 * 1024 * 2);
  bf16* vsb   = (bf16*)alloc((size_t)8192 * 1024 * 2);
  bf16* qb    = (bf16*)alloc((size_t)8192 * 1024 * 2);   // [b,h,s,dh]
  bf16* kb    = (bf16*)alloc((size_t)8192 * 1024 * 2);   // [b,h,s,dh]
  bf16* vbT   = (bf16*)alloc((size_t)8192 * 1024 * 2);   // [b,h,dh,s]
  bf16* outb  = (bf16*)alloc((size_t)8192 * 1024 * 2);   // [b,s,h,dh]
  // Ae (8192x4096 bf16 = 64 MB) overlays qsb..qb, all dead by the time expand_o runs
  bf16* Ae    = qsb;

  f32_to_bf16<<<1024, 256, 0, stream>>>((const float4*)wq, (bf16x4*)wqb, 262144);
  f32_to_bf16<<<1024, 256, 0, stream>>>((const float4*)wk, (bf16x4*)wkb, 262144);
  f32_to_bf16<<<8192, 256, 0, stream>>>((const float4*)q_src, (bf16x4*)qsb, 2097152);
  f32_to_bf16<<<8192, 256, 0, stream>>>((const float4*)k_src, (bf16x4*)ksb, 2097152);
  f32_to_bf16<<<8192, 256, 0, stream>>>((const float4*)v_src, (bf16x4*)vsb, 2097152);
  make_wvt<<<dim3(16, 2, 32), 256, 0, stream>>>(v_w, wvt);
  make_wot<<<dim3(16, 2, 32), 256, 0, stream>>>(o_w, wot);
  gating<<<dim3(8192, 2), 256, 0, stream>>>(q_src, k_src, sel_v_w, sel_o_w,
                                            bias_v, bias_o, gate_v, gate_o, out);

  const float ssq = 0.29730177875068026f;            // 128^-0.25 (applied to both q and k)
  const float log2e = 1.4426950408889634f;
  gemm_moe<0><<<dim3(8, 64), 256, 0, stream>>>(qsb, wqb, nullptr, qb, nullptr, ssq * log2e);
  gemm_moe<0><<<dim3(8, 64), 256, 0, stream>>>(ksb, wkb, nullptr, kb, nullptr, ssq);
  gemm_moe<1><<<dim3(1, 64, 8), 256, 0, stream>>>(vsb, wvt, gate_v, vbT, nullptr, 1.0f);
  attn_kernel<<<dim3(16, 32), 256, 0, stream>>>(qb, kb, vbT, outb);
  expand_o<<<16384, 256, 0, stream>>>(outb, gate_o, Ae);
  gemm_moe<2><<<dim3(8, 64), 256, 0, stream>>>(Ae, wot, nullptr, nullptr, out, 1.0f);
}

// Round 5
// 646.764 us; speedup vs baseline: 1.3831x; 1.0712x over previous
//
#include <hip/hip_runtime.h>
#include <cstdint>
#include <cstddef>

typedef __bf16 bf16;
typedef __bf16 bf16x4 __attribute__((ext_vector_type(4)));
typedef __bf16 bf16x8 __attribute__((ext_vector_type(8)));
typedef float  fx4    __attribute__((ext_vector_type(4)));

// Problem dims (fixed): B=4, S=2048, D=1024, H=8, E=4, DH=128, K_route=2

// async global->LDS DMA, 16 B per lane; dest = wave-uniform base + lane*16 (m97/m104)
__device__ __forceinline__ void async16(const bf16* g, bf16* l) {
  __builtin_amdgcn_global_load_lds((const __attribute__((address_space(1))) void*)g,
                                   (__attribute__((address_space(3))) void*)l, 16, 0, 0);
}

#define BARRIER() do { asm volatile("" ::: "memory"); __builtin_amdgcn_s_barrier(); \
                       asm volatile("" ::: "memory"); } while (0)

// DPP row-rotate (within 16-lane rows) — VALU-pipe cross-lane reduce (vs ds_bpermute).
template <int CTRL>
__device__ __forceinline__ float dppf(float x) {
  return __int_as_float(__builtin_amdgcn_update_dpp(
      0, __float_as_int(x), CTRL, 0xf, 0xf, true));
}

// vectorized f32 -> bf16 (G13: 16B/lane loads), n4 = n/4
__global__ __launch_bounds__(256) void f32_to_bf16(const float4* __restrict__ src,
                                                   bf16x4* __restrict__ dst, int n4) {
  int i = blockIdx.x * 256 + threadIdx.x;
  if (i < n4) {
    float4 v = src[i];
    bf16x4 o;
    o[0] = (bf16)v.x; o[1] = (bf16)v.y; o[2] = (bf16)v.z; o[3] = (bf16)v.w;
    dst[i] = o;
  }
}

// wvt[h][dh][e][k] <- v_w[h][e][k][dh]; LDS-tiled 64x64 transpose, coalesced both sides.
__global__ __launch_bounds__(256) void make_wvt(const float* __restrict__ v_w,
                                                bf16* __restrict__ wvt) {
  __shared__ float tile[64][65];
  const int he = blockIdx.z, k0 = blockIdx.x * 64, dh0 = blockIdx.y * 64;
  const float* in = v_w + (size_t)he * 1024 * 128;
  #pragma unroll
  for (int j = 0; j < 16; j++) {
    int idx = threadIdx.x + j * 256;
    int r = idx >> 6, c = idx & 63;                 // r=k, c=dh
    tile[r][c] = in[(size_t)(k0 + r) * 128 + dh0 + c];
  }
  __syncthreads();
  const int h = he >> 2, e = he & 3;
  bf16* outp = wvt + ((size_t)(h * 128 + dh0) * 4 + e) * 1024 + k0;
  #pragma unroll
  for (int j = 0; j < 16; j++) {
    int idx = threadIdx.x + j * 256;
    int r = idx >> 6, c = idx & 63;                 // r=dh, c=k
    outp[(size_t)r * 4096 + c] = (bf16)tile[c][r];
  }
}

// wot[d][h][e][dh] <- o_w[h][e][dh][d]
__global__ __launch_bounds__(256) void make_wot(const float* __restrict__ o_w,
                                                bf16* __restrict__ wot) {
  __shared__ float tile[64][65];
  const int he = blockIdx.z, d0 = blockIdx.x * 64, dh0 = blockIdx.y * 64;
  const float* in = o_w + (size_t)he * 128 * 1024;
  #pragma unroll
  for (int j = 0; j < 16; j++) {
    int idx = threadIdx.x + j * 256;
    int r = idx >> 6, c = idx & 63;                 // r=dh, c=d
    tile[r][c] = in[(size_t)(dh0 + r) * 1024 + d0 + c];
  }
  __syncthreads();
  bf16* outp = wot + (size_t)d0 * 4096 + he * 128 + dh0;
  #pragma unroll
  for (int j = 0; j < 16; j++) {
    int idx = threadIdx.x + j * 256;
    int r = idx >> 6, c = idx & 63;                 // r=d, c=dh
    outp[(size_t)r * 4096 + c] = (bf16)tile[c][r];
  }
}

// ---------------- gating: sigmoid + top-2 of 4 per (token, head), f64 for exact ranking --------
__global__ __launch_bounds__(256) void gating(const float* __restrict__ q_src,
                                              const float* __restrict__ k_src,
                                              const float* __restrict__ sel_v_w,
                                              const float* __restrict__ sel_o_w,
                                              const float* __restrict__ bias_v,
                                              const float* __restrict__ bias_o,
                                              float* __restrict__ gate_v,
                                              float* __restrict__ gate_o,
                                              float* __restrict__ d_out) {
  int m = blockIdx.x, g = blockIdx.y;
  const float* x = g ? q_src : k_src;
  const float* w = g ? sel_o_w : sel_v_w;
  const float* bias = g ? bias_o : bias_v;
  float* gate = g ? gate_o : gate_v;
  float* idxo = d_out + 8388608 + g * 131072;       // v_idx then o_idx, as float values

  __shared__ float xs[1024];
  __shared__ double part_s[32][8];
  __shared__ double sel_s[32];
  int t = threadIdx.x;
  #pragma unroll
  for (int p = 0; p < 4; p++) xs[t + p * 256] = x[(size_t)m * 1024 + t + p * 256];
  __syncthreads();
  int he = t >> 3, pp = t & 7;
  const float* wrow = w + he * 1024;
  double acc = 0.0;
  for (int j = 0; j < 128; j++) { int k = pp + j * 8; acc += (double)xs[k] * (double)wrow[k]; }
  part_s[he][pp] = acc;
  __syncthreads();
  if (t < 32) {
    double tot = 0.0;
    #pragma unroll
    for (int j = 0; j < 8; j++) tot += part_s[t][j];
    sel_s[t] = 1.0 / (1.0 + exp(-tot));
  }
  __syncthreads();
  if (t < 8) {
    double v[4], vbv[4];
    #pragma unroll
    for (int e = 0; e < 4; e++) { v[e] = sel_s[t * 4 + e]; vbv[e] = v[e] + (double)bias[e]; }
    int i0 = 0;
    for (int e = 1; e < 4; e++) if (vbv[e] > vbv[i0]) i0 = e;
    int i1 = -1; double best = -1e300;
    for (int e = 0; e < 4; e++) { if (e == i0) continue; if (vbv[e] > best) { best = vbv[e]; i1 = e; } }
    float* gp = gate + ((size_t)m * 8 + t) * 4;
    #pragma unroll
    for (int e = 0; e < 4; e++) {
      float gv = 0.f;
      if (e == i0) gv = (float)v[i0];
      else if (e == i1) gv = (float)v[i1];
      gp[e] = gv;
    }
    idxo[m * 16 + t * 2 + 0] = (float)i0;
    idxo[m * 16 + t * 2 + 1] = (float)i1;
  }
}

// expander: Ae[m][(h*4+e)*128+dh] = outb[m][h*128+dh] * gate_o[m][h][e]
__global__ __launch_bounds__(256) void expand_o(const bf16* __restrict__ outb,
                                                const float* __restrict__ gate_o,
                                                bf16* __restrict__ Ae) {
  int idx = blockIdx.x * 256 + threadIdx.x;   // unit = 8 bf16
  int m = idx >> 9;                           // 512 units per row
  int u = idx & 511;
  int he = u >> 4;                            // h*4+e
  int hh = he >> 2, e = he & 3;
  int dh0 = (u & 15) * 8;
  float gv = gate_o[((size_t)m * 8 + hh) * 4 + e];
  bf16x8 v = *(const bf16x8*)(outb + ((size_t)m * 8 + hh) * 128 + dh0);
  #pragma unroll
  for (int j = 0; j < 8; j++) v[j] = (bf16)((float)v[j] * gv);
  *(bf16x8*)(Ae + (size_t)m * 4096 + u * 8) = v;
}

// ---------------- GEMM: C[M x N] = A @ BT^T, bf16 MFMA 16x16x32 ----------------
// R5: 256x128 tile, 8 waves (512 thr), BK=64, double-buffered 96 KB LDS -> 1 block/CU,
// grid exactly 256 (full co-residency, no tail). Per K-step: stage next tile (6 DMAs/thr),
// counted vmcnt(6) (full K-step prefetch distance), then 4 phases of
// {ds_read subtile -> barrier -> setprio(1) -> 8 MFMA -> setprio(0) -> barrier} —
// the phase-split role diversity that gates T2/T5 (guide m218b/m224/m228e).
// T2 16B-chunk XOR swizzle kept (R4: conflicts 2.5e7 -> 1.3e5). 1D grid, bid&7 = N-panel
// (modes 0/2) or head (mode 1) -> XCD-clustered B panels (T1).
// MODE 0: K=1024, plain; epilogue *scale -> bf16 [b,h,s,dh]
// MODE 1: h=bid&7, K=4096; gate merge at each 1024 boundary; epilogue transpose -> vbT
// MODE 2: K=4096, plain (gate pre-applied by expand_o); epilogue f32 -> d_out
template <int MODE>
__global__ __launch_bounds__(512) void gemm_moe(const bf16* __restrict__ Abf,
                                                const bf16* __restrict__ BT,
                                                const float* __restrict__ gate,
                                                bf16* __restrict__ Cbf,
                                                float* __restrict__ Cf32,
                                                float scale) {
  constexpr int KDIM = (MODE == 0) ? 1024 : 4096;
  constexpr int ASTRIDE = (MODE == 2) ? 4096 : 1024;
  // [2][A 256x64] at 0, [2][B 128x64] at 32768 (bf16 units): 96 KB total
  __shared__ __align__(16) bf16 smem[49152];
  const int t = threadIdx.x;
  const int wave = t >> 6, lane = t & 63;
  const int wr = wave >> 1, wc = wave & 1;          // 4 M-groups x 2 N-groups
  const int quad = lane >> 4, l16 = lane & 15;
  const int bid = blockIdx.x;
  const int m0 = (bid >> 3) * 256;
  const int n0 = (MODE == 1) ? 0 : (bid & 7) * 128;
  const int h = (MODE == 1) ? (bid & 7) : 0;
  const bf16* BTh = (MODE == 1) ? BT + (size_t)h * 128 * 4096 : BT;

  fx4 acc[4][4] = {};    // per-wave 64x64 output (4 mi x 4 ni)
  fx4 accT[4][4] = {};   // gated total (mode 1 only; DCE'd otherwise)

  const int srow = t >> 3, sch = t & 7;   // staging: 64 rows x 8 chunks (16 B) per pass

  auto stage = [&](int buf, int k0) {
    bf16* As = smem + buf * 16384;
    bf16* Bs = smem + 32768 + buf * 8192;
    #pragma unroll
    for (int p = 0; p < 2; p++) {                    // B: 128 rows
      int row = p * 64 + srow;
      int sc = sch ^ (row & 7);
      async16(BTh + (size_t)(n0 + row) * KDIM + k0 + sc * 8,
              Bs + row * 64 + sch * 8);
    }
    int col = (MODE == 1) ? (k0 & 1023) : k0;
    #pragma unroll
    for (int p = 0; p < 4; p++) {                    // A: 256 rows
      int row = p * 64 + srow;
      int sc = sch ^ (row & 7);
      async16(Abf + (size_t)(m0 + row) * ASTRIDE + col + sc * 8,
              As + row * 64 + sch * 8);
    }
  };

  stage(0, 0);
  int buf = 0;
  for (int k0 = 0; k0 < KDIM; k0 += 64) {
    if (k0 + 64 < KDIM) {
      stage(buf ^ 1, k0 + 64);                         // prefetch next K-tile
      asm volatile("s_waitcnt vmcnt(6)" ::: "memory"); // wait current tile only
    } else {
      asm volatile("s_waitcnt vmcnt(0)" ::: "memory");
    }
    BARRIER();
    const bf16* As = smem + buf * 16384;
    const bf16* Bs = smem + 32768 + buf * 8192;
    #pragma unroll
    for (int kk = 0; kk < 64; kk += 32) {
      bf16x8 af[4], bfr[4];
      // phase A: A-frags + B-frags ni 0,1
      #pragma unroll
      for (int i = 0; i < 4; i++) {
        int ar = wr * 64 + i * 16 + l16;
        af[i] = *(const bf16x8*)(As + ar * 64 + ((((kk >> 3) + quad) ^ (ar & 7)) * 8));
      }
      #pragma unroll
      for (int i = 0; i < 2; i++) {
        int br = wc * 64 + i * 16 + l16;
        bfr[i] = *(const bf16x8*)(Bs + br * 64 + ((((kk >> 3) + quad) ^ (br & 7)) * 8));
      }
      BARRIER();
      __builtin_amdgcn_s_setprio(1);
      #pragma unroll
      for (int mi = 0; mi < 4; mi++)
        #pragma unroll
        for (int ni = 0; ni < 2; ni++)
          acc[mi][ni] = __builtin_amdgcn_mfma_f32_16x16x32_bf16(af[mi], bfr[ni], acc[mi][ni], 0, 0, 0);
      __builtin_amdgcn_s_setprio(0);
      BARRIER();
      // phase B: B-frags ni 2,3 (af held in regs)
      #pragma unroll
      for (int i = 2; i < 4; i++) {
        int br = wc * 64 + i * 16 + l16;
        bfr[i] = *(const bf16x8*)(Bs + br * 64 + ((((kk >> 3) + quad) ^ (br & 7)) * 8));
      }
      BARRIER();
      __builtin_amdgcn_s_setprio(1);
      #pragma unroll
      for (int mi = 0; mi < 4; mi++)
        #pragma unroll
        for (int ni = 2; ni < 4; ni++)
          acc[mi][ni] = __builtin_amdgcn_mfma_f32_16x16x32_bf16(af[mi], bfr[ni], acc[mi][ni], 0, 0, 0);
      __builtin_amdgcn_s_setprio(0);
      BARRIER();
    }
    if constexpr (MODE == 1) {
      if (((k0 + 64) & 1023) == 0) {     // expert-chunk boundary: 4 merges total
        const int e = k0 >> 10;
        #pragma unroll
        for (int mi = 0; mi < 4; mi++)
          #pragma unroll
          for (int r = 0; r < 4; r++) {
            int m = m0 + wr * 64 + mi * 16 + quad * 4 + r;
            float gv = gate[((size_t)m * 8 + h) * 4 + e];
            #pragma unroll
            for (int ni = 0; ni < 4; ni++)
              accT[mi][ni][r] += gv * acc[mi][ni][r];
          }
        #pragma unroll
        for (int mi = 0; mi < 4; mi++)
          #pragma unroll
          for (int ni = 0; ni < 4; ni++)
            #pragma unroll
            for (int j = 0; j < 4; j++) acc[mi][ni][j] = 0.f;
      }
    }
    buf ^= 1;
  }

  if (MODE == 1) {
    // transpose through LDS -> vbT[b,h,dh,s] with coalesced global writes
    // T[dh 128][m 256] stride 264 bf16 = 67584 B <= 98304 (reuse smem; all reads done)
    #pragma unroll
    for (int mi = 0; mi < 4; mi++)
      #pragma unroll
      for (int ni = 0; ni < 4; ni++) {
        int nl = wc * 64 + ni * 16 + l16;
        int ml = wr * 64 + mi * 16 + quad * 4;
        bf16x4 pk;
        #pragma unroll
        for (int r = 0; r < 4; r++) pk[r] = (bf16)accT[mi][ni][r];
        *(bf16x4*)(smem + nl * 264 + ml) = pk;
      }
    __syncthreads();
    int b = m0 >> 11, s0 = m0 & 2047;
    const int row = t >> 2, seg = t & 3;
    bf16* dst = Cbf + (((size_t)(b * 8 + h) * 128) + row) * 2048 + s0 + seg * 64;
    #pragma unroll
    for (int j = 0; j < 8; j++)
      *(float4*)(dst + j * 8) = *(float4*)(smem + row * 264 + seg * 64 + j * 8);
    return;
  }

  // epilogue: C/D layout col=lane&15, row=quad*4+reg
  #pragma unroll
  for (int mi = 0; mi < 4; mi++)
    #pragma unroll
    for (int ni = 0; ni < 4; ni++)
      #pragma unroll
      for (int r = 0; r < 4; r++) {
        int m = m0 + wr * 64 + mi * 16 + quad * 4 + r;
        int n = n0 + wc * 64 + ni * 16 + l16;
        float v = acc[mi][ni][r] * scale;
        if (MODE == 0) {
          int b = m >> 11, s = m & 2047, hh = n >> 7, dh = n & 127;
          Cbf[(((size_t)(b * 8 + hh) * 2048 + s) << 7) + dh] = (bf16)v;
        } else {
          Cf32[(size_t)m * 1024 + n] = v;
        }
      }
}

// ---------------- flash attention (causal) ----------------
// R1: double-buffered K/V via global_load_lds DMA, counted vmcnt(8), raw s_barrier,
//     both-sides 16B-chunk XOR swizzle. R2: DPP row_ror softmax reductions.
// R3: perfect balance + full co-residency: grid (16,32); block x runs q-tiles (31-x)
//     then (x) = exactly 33 KV-iterations every block; 512 blocks = exactly 2/CU.
__global__ __launch_bounds__(256) void attn_kernel(const bf16* __restrict__ qb,
                                                   const bf16* __restrict__ kb,
                                                   const bf16* __restrict__ vbT,
                                                   bf16* __restrict__ outb) {
  const int bh = blockIdx.y;
  const int b = bh >> 3, h = bh & 7;
  __shared__ __align__(16) bf16 Ks[2][64 * 128];    // [buf][k-row * 128 + dh], swizzled
  __shared__ __align__(16) bf16 VTs[2][128 * 64];   // [buf][dh-row * 64 + s], swizzled
  __shared__ __align__(16) bf16 Ps[4][16][72];
  const int t = threadIdx.x, wave = t >> 6, lane = t & 63;
  const int quad = lane >> 4, l16 = lane & 15;
  const bf16* qbase  = qb  + (size_t)bh * 2048 * 128;
  const bf16* kbase  = kb  + (size_t)bh * 2048 * 128;
  const bf16* vtbase = vbT + (size_t)bh * 128 * 2048;

  auto stage = [&](int buf, int kt) {
    #pragma unroll
    for (int p = 0; p < 4; p++) {
      int o = p * 4096 + wave * 1024 + lane * 16;        // byte offset in 16 KiB tile
      int kr = o >> 8, kc = o & 255;                     // 256 B rows (128 bf16)
      async16((const bf16*)((const char*)kbase + (size_t)(kt * 64 + kr) * 256 + (kc ^ ((kr & 7) << 4))),
              (bf16*)((char*)&Ks[buf][0] + o));
    }
    #pragma unroll
    for (int p = 0; p < 4; p++) {
      int o = p * 4096 + wave * 1024 + lane * 16;
      int vr = o >> 7, vc = o & 127;                     // 128 B rows (64 bf16)
      async16((const bf16*)((const char*)vtbase + (size_t)vr * 4096 + kt * 128 + (vc ^ ((vr & 7) << 4))),
              (bf16*)((char*)&VTs[buf][0] + o));
    }
  };

  #pragma unroll 1
  for (int pass = 0; pass < 2; pass++) {
    const int qt = pass ? blockIdx.x : (31 - blockIdx.x);   // heavy tile first

    bf16x8 qf[4];
    #pragma unroll
    for (int dk = 0; dk < 4; dk++)
      qf[dk] = *(const bf16x8*)(qbase + (size_t)(qt * 64 + wave * 16 + l16) * 128 + dk * 32 + quad * 8);

    float m_run[4], l_run[4];
    fx4 acc_o[8] = {};
    #pragma unroll
    for (int r = 0; r < 4; r++) { m_run[r] = -1e30f; l_run[r] = 0.f; }

    stage(0, 0);
    int cur = 0;

    for (int kt = 0; kt <= qt; kt++) {
      if (kt < qt) {
        stage(cur ^ 1, kt + 1);                            // prefetch next tile
        asm volatile("s_waitcnt vmcnt(8)" ::: "memory");   // wait tile kt only
      } else {
        asm volatile("s_waitcnt vmcnt(0)" ::: "memory");
      }
      __builtin_amdgcn_s_barrier();
      asm volatile("" ::: "memory");

      const char* Ksb  = (const char*)&Ks[cur][0];
      const char* VTsb = (const char*)&VTs[cur][0];

      fx4 accs[4] = {};
      __builtin_amdgcn_s_setprio(1);
      #pragma unroll
      for (int ni = 0; ni < 4; ni++)
        #pragma unroll
        for (int dk = 0; dk < 4; dk++) {
          int r = ni * 16 + l16;
          bf16x8 kf = *(const bf16x8*)(Ksb + r * 256 + ((dk * 64 + quad * 16) ^ ((r & 7) << 4)));
          accs[ni] = __builtin_amdgcn_mfma_f32_16x16x32_bf16(qf[dk], kf, accs[ni], 0, 0, 0);
        }
      __builtin_amdgcn_s_setprio(0);

      if (kt == qt) {   // causal mask on the diagonal tile
        #pragma unroll
        for (int ni = 0; ni < 4; ni++)
          #pragma unroll
          for (int r = 0; r < 4; r++) {
            int qr = wave * 16 + quad * 4 + r;
            int kc = ni * 16 + l16;
            if (kc > qr) accs[ni][r] = -1e30f;
          }
      }

      // softmax in exp2 domain (log2e folded into Q scale); DPP row_ror reductions
      #pragma unroll
      for (int r = 0; r < 4; r++) {
        float mx = fmaxf(fmaxf(accs[0][r], accs[1][r]), fmaxf(accs[2][r], accs[3][r]));
        mx = fmaxf(mx, dppf<0x121>(mx));   // row_ror:1
        mx = fmaxf(mx, dppf<0x122>(mx));   // row_ror:2
        mx = fmaxf(mx, dppf<0x124>(mx));   // row_ror:4
        mx = fmaxf(mx, dppf<0x128>(mx));   // row_ror:8
        float m_new = fmaxf(m_run[r], mx);
        float alpha = __builtin_amdgcn_exp2f(m_run[r] - m_new);
        float rs = 0.f;
        #pragma unroll
        for (int ni = 0; ni < 4; ni++) {
          float p = __builtin_amdgcn_exp2f(accs[ni][r] - m_new);
          accs[ni][r] = p; rs += p;
        }
        rs += dppf<0x121>(rs);
        rs += dppf<0x122>(rs);
        rs += dppf<0x124>(rs);
        rs += dppf<0x128>(rs);
        l_run[r] = l_run[r] * alpha + rs;
        m_run[r] = m_new;
        #pragma unroll
        for (int nj = 0; nj < 8; nj++) acc_o[nj][r] *= alpha;
      }

      // P: C-layout -> LDS -> A-layout (per-wave region; DS in-order within a wave)
      #pragma unroll
      for (int ni = 0; ni < 4; ni++)
        #pragma unroll
        for (int r = 0; r < 4; r++)
          Ps[wave][quad * 4 + r][ni * 16 + l16] = (bf16)accs[ni][r];

      __builtin_amdgcn_s_setprio(1);
      #pragma unroll
      for (int step = 0; step < 2; step++) {
        bf16x8 pf = *(const bf16x8*)&Ps[wave][l16][step * 32 + quad * 8];
        #pragma unroll
        for (int nj = 0; nj < 8; nj++) {
          int r = nj * 16 + l16;
          bf16x8 vf = *(const bf16x8*)(VTsb + r * 128 + ((step * 64 + quad * 16) ^ ((r & 7) << 4)));
          acc_o[nj] = __builtin_amdgcn_mfma_f32_16x16x32_bf16(pf, vf, acc_o[nj], 0, 0, 0);
        }
      }
      __builtin_amdgcn_s_setprio(0);

      asm volatile("" ::: "memory");
      __builtin_amdgcn_s_barrier();   // all waves done reading buf[cur] before re-stage
      cur ^= 1;
    }

    #pragma unroll
    for (int nj = 0; nj < 8; nj++)
      #pragma unroll
      for (int r = 0; r < 4; r++) {
        int s = qt * 64 + wave * 16 + quad * 4 + r;
        int token = b * 2048 + s;
        float o = acc_o[nj][r] / l_run[r];
        outb[((size_t)token * 8 + h) * 128 + nj * 16 + l16] = (bf16)o;
      }
  }
}

// ---------------- launch ----------------
extern "C" void kernel_launch(void* const* d_in, const int* in_sizes, int n_in,
                              void* d_out, int out_size, void* d_ws, size_t ws_size,
                              hipStream_t stream) {
  const float* q_src  = (const float*)d_in[0];
  const float* k_src  = (const float*)d_in[1];
  const float* v_src  = (const float*)d_in[2];
  const float* wq     = (const float*)d_in[3];
  const float* wk     = (const float*)d_in[4];
  const float* sel_v_w = (const float*)d_in[5];
  const float* sel_o_w = (const float*)d_in[6];
  const float* v_w    = (const float*)d_in[7];
  const float* o_w    = (const float*)d_in[8];
  const float* bias_v = (const float*)d_in[9];
  const float* bias_o = (const float*)d_in[10];
  float* out = (float*)d_out;

  char* ws = (char*)d_ws;
  size_t off = 0;
  auto alloc = [&](size_t bytes) { char* p = ws + off; off += (bytes + 255) & ~(size_t)255; return p; };
  bf16* wqb   = (bf16*)alloc((size_t)1024 * 1024 * 2);
  bf16* wkb   = (bf16*)alloc((size_t)1024 * 1024 * 2);
  bf16* wvt   = (bf16*)alloc((size_t)8 * 128 * 4 * 1024 * 2);
  bf16* wot   = (bf16*)alloc((size_t)1024 * 4096 * 2);
  float* gate_v = (float*)alloc((size_t)8192 * 32 * 4);
  float* gate_o = (float*)alloc((size_t)8192 * 32 * 4);
  bf16* qsb   = (bf16*)alloc((size_t)8192 * 1024 * 2);   // bf16 copies of srcs
  bf16* ksb   = (bf16*)alloc((size_t)8192 * 1024 * 2);
  bf16* vsb   = (bf16*)alloc((size_t)8192 * 1024 * 2);
  bf16* qb    = (bf16*)alloc((size_t)8192 * 1024 * 2);   // [b,h,s,dh]
  bf16* kb    = (bf16*)alloc((size_t)8192 * 1024 * 2);   // [b,h,s,dh]
  bf16* vbT   = (bf16*)alloc((size_t)8192 * 1024 * 2);   // [b,h,dh,s]
  bf16* outb  = (bf16*)alloc((size_t)8192 * 1024 * 2);   // [b,s,h,dh]
  // Ae (8192x4096 bf16 = 64 MB) overlays qsb..qb, all dead by the time expand_o runs
  bf16* Ae    = qsb;

  f32_to_bf16<<<1024, 256, 0, stream>>>((const float4*)wq, (bf16x4*)wqb, 262144);
  f32_to_bf16<<<1024, 256, 0, stream>>>((const float4*)wk, (bf16x4*)wkb, 262144);
  f32_to_bf16<<<8192, 256, 0, stream>>>((const float4*)q_src, (bf16x4*)qsb, 2097152);
  f32_to_bf16<<<8192, 256, 0, stream>>>((const float4*)k_src, (bf16x4*)ksb, 2097152);
  f32_to_bf16<<<8192, 256, 0, stream>>>((const float4*)v_src, (bf16x4*)vsb, 2097152);
  make_wvt<<<dim3(16, 2, 32), 256, 0, stream>>>(v_w, wvt);
  make_wot<<<dim3(16, 2, 32), 256, 0, stream>>>(o_w, wot);
  gating<<<dim3(8192, 2), 256, 0, stream>>>(q_src, k_src, sel_v_w, sel_o_w,
                                            bias_v, bias_o, gate_v, gate_o, out);

  const float ssq = 0.29730177875068026f;            // 128^-0.25 (applied to both q and k)
  const float log2e = 1.4426950408889634f;
  gemm_moe<0><<<256, 512, 0, stream>>>(qsb, wqb, nullptr, qb, nullptr, ssq * log2e);
  gemm_moe<0><<<256, 512, 0, stream>>>(ksb, wkb, nullptr, kb, nullptr, ssq);
  gemm_moe<1><<<256, 512, 0, stream>>>(vsb, wvt, gate_v, vbT, nullptr, 1.0f);
  attn_kernel<<<dim3(16, 32), 256, 0, stream>>>(qb, kb, vbT, outb);
  expand_o<<<16384, 256, 0, stream>>>(outb, gate_o, Ae);
  gemm_moe<2><<<256, 512, 0, stream>>>(Ae, wot, nullptr, nullptr, out, 1.0f);
}

// Round 6
// 597.356 us; speedup vs baseline: 1.4975x; 1.0827x over previous
//
#include <hip/hip_runtime.h>
#include <cstdint>
#include <cstddef>

typedef __bf16 bf16;
typedef __bf16 bf16x4 __attribute__((ext_vector_type(4)));
typedef __bf16 bf16x8 __attribute__((ext_vector_type(8)));
typedef float  fx4    __attribute__((ext_vector_type(4)));

// Problem dims (fixed): B=4, S=2048, D=1024, H=8, E=4, DH=128, K_route=2

// async global->LDS DMA, 16 B per lane; dest = wave-uniform base + lane*16 (m97/m104)
__device__ __forceinline__ void async16(const void* g, void* l) {
  __builtin_amdgcn_global_load_lds((const __attribute__((address_space(1))) void*)g,
                                   (__attribute__((address_space(3))) void*)l, 16, 0, 0);
}

#define BARRIER() do { asm volatile("" ::: "memory"); __builtin_amdgcn_s_barrier(); \
                       asm volatile("" ::: "memory"); } while (0)

// DPP row-rotate (within 16-lane rows) — VALU-pipe cross-lane reduce (vs ds_bpermute).
template <int CTRL>
__device__ __forceinline__ float dppf(float x) {
  return __int_as_float(__builtin_amdgcn_update_dpp(
      0, __float_as_int(x), CTRL, 0xf, 0xf, true));
}

// vectorized f32 -> bf16 (G13: 16B/lane loads), n4 = n/4
__global__ __launch_bounds__(256) void f32_to_bf16(const float4* __restrict__ src,
                                                   bf16x4* __restrict__ dst, int n4) {
  int i = blockIdx.x * 256 + threadIdx.x;
  if (i < n4) {
    float4 v = src[i];
    bf16x4 o;
    o[0] = (bf16)v.x; o[1] = (bf16)v.y; o[2] = (bf16)v.z; o[3] = (bf16)v.w;
    dst[i] = o;
  }
}

// wvt[h][dh][e][k] <- v_w[h][e][k][dh]; LDS-tiled 64x64 transpose, coalesced both sides.
__global__ __launch_bounds__(256) void make_wvt(const float* __restrict__ v_w,
                                                bf16* __restrict__ wvt) {
  __shared__ float tile[64][65];
  const int he = blockIdx.z, k0 = blockIdx.x * 64, dh0 = blockIdx.y * 64;
  const float* in = v_w + (size_t)he * 1024 * 128;
  #pragma unroll
  for (int j = 0; j < 16; j++) {
    int idx = threadIdx.x + j * 256;
    int r = idx >> 6, c = idx & 63;                 // r=k, c=dh
    tile[r][c] = in[(size_t)(k0 + r) * 128 + dh0 + c];
  }
  __syncthreads();
  const int h = he >> 2, e = he & 3;
  bf16* outp = wvt + ((size_t)(h * 128 + dh0) * 4 + e) * 1024 + k0;
  #pragma unroll
  for (int j = 0; j < 16; j++) {
    int idx = threadIdx.x + j * 256;
    int r = idx >> 6, c = idx & 63;                 // r=dh, c=k
    outp[(size_t)r * 4096 + c] = (bf16)tile[c][r];
  }
}

// wot[d][h][e][dh] <- o_w[h][e][dh][d]
__global__ __launch_bounds__(256) void make_wot(const float* __restrict__ o_w,
                                                bf16* __restrict__ wot) {
  __shared__ float tile[64][65];
  const int he = blockIdx.z, d0 = blockIdx.x * 64, dh0 = blockIdx.y * 64;
  const float* in = o_w + (size_t)he * 128 * 1024;
  #pragma unroll
  for (int j = 0; j < 16; j++) {
    int idx = threadIdx.x + j * 256;
    int r = idx >> 6, c = idx & 63;                 // r=dh, c=d
    tile[r][c] = in[(size_t)(dh0 + r) * 1024 + d0 + c];
  }
  __syncthreads();
  bf16* outp = wot + (size_t)d0 * 4096 + he * 128 + dh0;
  #pragma unroll
  for (int j = 0; j < 16; j++) {
    int idx = threadIdx.x + j * 256;
    int r = idx >> 6, c = idx & 63;                 // r=d, c=dh
    outp[(size_t)r * 4096 + c] = (bf16)tile[c][r];
  }
}

// ---------------- gating v2 (R6) ----------------
// Was: 16384 blocks, per-thread 128-iter serial loop of scalar ds_read_b32 +
// global_load_dword + 2 cvt + f64 fma (536M products x 2 scalar reads = issue/LDS-bound,
// 136 us). Now: register-blocked LDS-staged mini-GEMM: 64 tokens x 32 (h,e) rows per
// block, grid (128,2) = 1 block/CU; K chunks of 128 f32 double-buffered (96 KB LDS) via
// global_load_lds + counted vmcnt(12); XOR-swizzled rows (conflict-free ds_read_b128 with
// 8-way broadcast); thread = 2 tok x 1 head (4 experts): 6 float4 reads per 32 products,
// f64 accumulation with cvts shared across the register block (exact ranking preserved).
// Sigmoid in f32 exp2 (error ~1e-7 << ranking margins and << 0.015 tolerance).
__global__ __launch_bounds__(256) void gating(const float* __restrict__ q_src,
                                              const float* __restrict__ k_src,
                                              const float* __restrict__ sel_v_w,
                                              const float* __restrict__ sel_o_w,
                                              const float* __restrict__ bias_v,
                                              const float* __restrict__ bias_o,
                                              float* __restrict__ gate_v,
                                              float* __restrict__ gate_o,
                                              float* __restrict__ d_out) {
  const int g = blockIdx.y;
  const int m0 = blockIdx.x * 64;
  const float* x = g ? q_src : k_src;
  const float* w = g ? sel_o_w : sel_v_w;
  const float* bias = g ? bias_o : bias_v;
  float* gate = g ? gate_o : gate_v;
  float* idxo = d_out + 8388608 + g * 131072;       // v_idx then o_idx, as float values

  // [buf][ xs 64x128 f32 | ws 32x128 f32 ] = 2 x 48 KB
  __shared__ __align__(16) float smem[2 * 12288];

  const int t = threadIdx.x;
  const int hg = t & 7;          // head
  const int tg = t >> 3;         // token pair 0..31

  auto stage = [&](int buf, int k0) {
    float* xs = smem + buf * 12288;
    float* ws = xs + 8192;
    #pragma unroll
    for (int p = 0; p < 8; p++) {                    // xs: 64 rows x 128 f32
      int of = p * 1024 + t * 4;
      int row = of >> 7, c = (of >> 2) & 31;
      int sc = c ^ ((row >> 1) & 7);                 // pre-swizzled source chunk
      async16(x + (size_t)(m0 + row) * 1024 + k0 + sc * 4, xs + of);
    }
    #pragma unroll
    for (int p = 0; p < 4; p++) {                    // ws: 32 rows x 128 f32
      int of = p * 1024 + t * 4;
      int row = of >> 7, c = (of >> 2) & 31;
      int sc = c ^ ((row >> 2) & 7);
      async16(w + (size_t)row * 1024 + k0 + sc * 4, ws + of);
    }
  };

  double acc[2][4] = {};

  stage(0, 0);
  int buf = 0;
  for (int c8 = 0; c8 < 8; c8++) {
    if (c8 < 7) {
      stage(buf ^ 1, (c8 + 1) * 128);                  // prefetch next chunk
      asm volatile("s_waitcnt vmcnt(12)" ::: "memory"); // wait current chunk only
    } else {
      asm volatile("s_waitcnt vmcnt(0)" ::: "memory");
    }
    BARRIER();
    const float* xs = smem + buf * 12288;
    const float* ws = xs + 8192;
    const int xr0 = tg * 2;
    #pragma unroll 4
    for (int k4 = 0; k4 < 32; k4++) {
      float4 x0 = *(const float4*)(xs + (size_t)xr0 * 128 + (size_t)((k4 ^ (tg & 7)) * 4));
      float4 x1 = *(const float4*)(xs + (size_t)(xr0 + 1) * 128 + (size_t)((k4 ^ (tg & 7)) * 4));
      double x0d[4] = {(double)x0.x, (double)x0.y, (double)x0.z, (double)x0.w};
      double x1d[4] = {(double)x1.x, (double)x1.y, (double)x1.z, (double)x1.w};
      #pragma unroll
      for (int e = 0; e < 4; e++) {
        int wr = hg * 4 + e;
        float4 wv = *(const float4*)(ws + (size_t)wr * 128 + (size_t)((k4 ^ hg) * 4));
        double w0 = (double)wv.x, w1 = (double)wv.y, w2 = (double)wv.z, w3 = (double)wv.w;
        acc[0][e] += x0d[0] * w0 + x0d[1] * w1 + x0d[2] * w2 + x0d[3] * w3;
        acc[1][e] += x1d[0] * w0 + x1d[1] * w1 + x1d[2] * w2 + x1d[3] * w3;
      }
    }
    BARRIER();   // all waves done with buf before it is re-staged next iteration
    buf ^= 1;
  }

  const float log2e = 1.4426950408889634f;
  float b0 = bias[0], b1 = bias[1], b2 = bias[2], b3 = bias[3];
  #pragma unroll
  for (int tok = 0; tok < 2; tok++) {
    int m = m0 + tg * 2 + tok;
    float sel[4];
    #pragma unroll
    for (int e = 0; e < 4; e++) {
      float lv = (float)acc[tok][e];
      sel[e] = 1.0f / (1.0f + __builtin_amdgcn_exp2f(-lv * log2e));
    }
    float vb[4] = {sel[0] + b0, sel[1] + b1, sel[2] + b2, sel[3] + b3};
    int i0 = 0;
    #pragma unroll
    for (int e = 1; e < 4; e++) if (vb[e] > vb[i0]) i0 = e;
    int i1 = -1; float best = -1e30f;
    #pragma unroll
    for (int e = 0; e < 4; e++) { if (e == i0) continue; if (vb[e] > best) { best = vb[e]; i1 = e; } }
    float4 gv;
    gv.x = (i0 == 0 || i1 == 0) ? sel[0] : 0.f;
    gv.y = (i0 == 1 || i1 == 1) ? sel[1] : 0.f;
    gv.z = (i0 == 2 || i1 == 2) ? sel[2] : 0.f;
    gv.w = (i0 == 3 || i1 == 3) ? sel[3] : 0.f;
    *(float4*)(gate + ((size_t)m * 8 + hg) * 4) = gv;
    idxo[m * 16 + hg * 2 + 0] = (float)i0;
    idxo[m * 16 + hg * 2 + 1] = (float)i1;
  }
}

// expander: Ae[m][(h*4+e)*128+dh] = outb[m][h*128+dh] * gate_o[m][h][e]
__global__ __launch_bounds__(256) void expand_o(const bf16* __restrict__ outb,
                                                const float* __restrict__ gate_o,
                                                bf16* __restrict__ Ae) {
  int idx = blockIdx.x * 256 + threadIdx.x;   // unit = 8 bf16
  int m = idx >> 9;                           // 512 units per row
  int u = idx & 511;
  int he = u >> 4;                            // h*4+e
  int hh = he >> 2, e = he & 3;
  int dh0 = (u & 15) * 8;
  float gv = gate_o[((size_t)m * 8 + hh) * 4 + e];
  bf16x8 v = *(const bf16x8*)(outb + ((size_t)m * 8 + hh) * 128 + dh0);
  #pragma unroll
  for (int j = 0; j < 8; j++) v[j] = (bf16)((float)v[j] * gv);
  *(bf16x8*)(Ae + (size_t)m * 4096 + u * 8) = v;
}

// ---------------- GEMM: C[M x N] = A @ BT^T, bf16 MFMA 16x16x32 ----------------
// R5: 256x128 tile, 8 waves (512 thr), BK=64, double-buffered 96 KB LDS -> 1 block/CU,
// grid exactly 256 (full co-residency, no tail). Per K-step: stage next tile (6 DMAs/thr),
// counted vmcnt(6) (full K-step prefetch distance), then 4 phases of
// {ds_read subtile -> barrier -> setprio(1) -> 8 MFMA -> setprio(0) -> barrier} —
// the phase-split role diversity that gates T2/T5 (guide m218b/m224/m228e).
// T2 16B-chunk XOR swizzle kept (R4: conflicts 2.5e7 -> 1.3e5). 1D grid, bid&7 = N-panel
// (modes 0/2) or head (mode 1) -> XCD-clustered B panels (T1).
// MODE 0: K=1024, plain; epilogue *scale -> bf16 [b,h,s,dh]
// MODE 1: h=bid&7, K=4096; gate merge at each 1024 boundary; epilogue transpose -> vbT
// MODE 2: K=4096, plain (gate pre-applied by expand_o); epilogue f32 -> d_out
template <int MODE>
__global__ __launch_bounds__(512) void gemm_moe(const bf16* __restrict__ Abf,
                                                const bf16* __restrict__ BT,
                                                const float* __restrict__ gate,
                                                bf16* __restrict__ Cbf,
                                                float* __restrict__ Cf32,
                                                float scale) {
  constexpr int KDIM = (MODE == 0) ? 1024 : 4096;
  constexpr int ASTRIDE = (MODE == 2) ? 4096 : 1024;
  // [2][A 256x64] at 0, [2][B 128x64] at 32768 (bf16 units): 96 KB total
  __shared__ __align__(16) bf16 smem[49152];
  const int t = threadIdx.x;
  const int wave = t >> 6, lane = t & 63;
  const int wr = wave >> 1, wc = wave & 1;          // 4 M-groups x 2 N-groups
  const int quad = lane >> 4, l16 = lane & 15;
  const int bid = blockIdx.x;
  const int m0 = (bid >> 3) * 256;
  const int n0 = (MODE == 1) ? 0 : (bid & 7) * 128;
  const int h = (MODE == 1) ? (bid & 7) : 0;
  const bf16* BTh = (MODE == 1) ? BT + (size_t)h * 128 * 4096 : BT;

  fx4 acc[4][4] = {};    // per-wave 64x64 output (4 mi x 4 ni)
  fx4 accT[4][4] = {};   // gated total (mode 1 only; DCE'd otherwise)

  const int srow = t >> 3, sch = t & 7;   // staging: 64 rows x 8 chunks (16 B) per pass

  auto stage = [&](int buf, int k0) {
    bf16* As = smem + buf * 16384;
    bf16* Bs = smem + 32768 + buf * 8192;
    #pragma unroll
    for (int p = 0; p < 2; p++) {                    // B: 128 rows
      int row = p * 64 + srow;
      int sc = sch ^ (row & 7);
      async16(BTh + (size_t)(n0 + row) * KDIM + k0 + sc * 8,
              Bs + row * 64 + sch * 8);
    }
    int col = (MODE == 1) ? (k0 & 1023) : k0;
    #pragma unroll
    for (int p = 0; p < 4; p++) {                    // A: 256 rows
      int row = p * 64 + srow;
      int sc = sch ^ (row & 7);
      async16(Abf + (size_t)(m0 + row) * ASTRIDE + col + sc * 8,
              As + row * 64 + sch * 8);
    }
  };

  stage(0, 0);
  int buf = 0;
  for (int k0 = 0; k0 < KDIM; k0 += 64) {
    if (k0 + 64 < KDIM) {
      stage(buf ^ 1, k0 + 64);                         // prefetch next K-tile
      asm volatile("s_waitcnt vmcnt(6)" ::: "memory"); // wait current tile only
    } else {
      asm volatile("s_waitcnt vmcnt(0)" ::: "memory");
    }
    BARRIER();
    const bf16* As = smem + buf * 16384;
    const bf16* Bs = smem + 32768 + buf * 8192;
    #pragma unroll
    for (int kk = 0; kk < 64; kk += 32) {
      bf16x8 af[4], bfr[4];
      // phase A: A-frags + B-frags ni 0,1
      #pragma unroll
      for (int i = 0; i < 4; i++) {
        int ar = wr * 64 + i * 16 + l16;
        af[i] = *(const bf16x8*)(As + ar * 64 + ((((kk >> 3) + quad) ^ (ar & 7)) * 8));
      }
      #pragma unroll
      for (int i = 0; i < 2; i++) {
        int br = wc * 64 + i * 16 + l16;
        bfr[i] = *(const bf16x8*)(Bs + br * 64 + ((((kk >> 3) + quad) ^ (br & 7)) * 8));
      }
      BARRIER();
      __builtin_amdgcn_s_setprio(1);
      #pragma unroll
      for (int mi = 0; mi < 4; mi++)
        #pragma unroll
        for (int ni = 0; ni < 2; ni++)
          acc[mi][ni] = __builtin_amdgcn_mfma_f32_16x16x32_bf16(af[mi], bfr[ni], acc[mi][ni], 0, 0, 0);
      __builtin_amdgcn_s_setprio(0);
      BARRIER();
      // phase B: B-frags ni 2,3 (af held in regs)
      #pragma unroll
      for (int i = 2; i < 4; i++) {
        int br = wc * 64 + i * 16 + l16;
        bfr[i] = *(const bf16x8*)(Bs + br * 64 + ((((kk >> 3) + quad) ^ (br & 7)) * 8));
      }
      BARRIER();
      __builtin_amdgcn_s_setprio(1);
      #pragma unroll
      for (int mi = 0; mi < 4; mi++)
        #pragma unroll
        for (int ni = 2; ni < 4; ni++)
          acc[mi][ni] = __builtin_amdgcn_mfma_f32_16x16x32_bf16(af[mi], bfr[ni], acc[mi][ni], 0, 0, 0);
      __builtin_amdgcn_s_setprio(0);
      BARRIER();
    }
    if constexpr (MODE == 1) {
      if (((k0 + 64) & 1023) == 0) {     // expert-chunk boundary: 4 merges total
        const int e = k0 >> 10;
        #pragma unroll
        for (int mi = 0; mi < 4; mi++)
          #pragma unroll
          for (int r = 0; r < 4; r++) {
            int m = m0 + wr * 64 + mi * 16 + quad * 4 + r;
            float gv = gate[((size_t)m * 8 + h) * 4 + e];
            #pragma unroll
            for (int ni = 0; ni < 4; ni++)
              accT[mi][ni][r] += gv * acc[mi][ni][r];
          }
        #pragma unroll
        for (int mi = 0; mi < 4; mi++)
          #pragma unroll
          for (int ni = 0; ni < 4; ni++)
            #pragma unroll
            for (int j = 0; j < 4; j++) acc[mi][ni][j] = 0.f;
      }
    }
    buf ^= 1;
  }

  if (MODE == 1) {
    // transpose through LDS -> vbT[b,h,dh,s] with coalesced global writes
    // T[dh 128][m 256] stride 264 bf16 = 67584 B <= 98304 (reuse smem; all reads done)
    #pragma unroll
    for (int mi = 0; mi < 4; mi++)
      #pragma unroll
      for (int ni = 0; ni < 4; ni++) {
        int nl = wc * 64 + ni * 16 + l16;
        int ml = wr * 64 + mi * 16 + quad * 4;
        bf16x4 pk;
        #pragma unroll
        for (int r = 0; r < 4; r++) pk[r] = (bf16)accT[mi][ni][r];
        *(bf16x4*)(smem + nl * 264 + ml) = pk;
      }
    __syncthreads();
    int b = m0 >> 11, s0 = m0 & 2047;
    const int row = t >> 2, seg = t & 3;
    bf16* dst = Cbf + (((size_t)(b * 8 + h) * 128) + row) * 2048 + s0 + seg * 64;
    #pragma unroll
    for (int j = 0; j < 8; j++)
      *(float4*)(dst + j * 8) = *(float4*)(smem + row * 264 + seg * 64 + j * 8);
    return;
  }

  // epilogue: C/D layout col=lane&15, row=quad*4+reg
  #pragma unroll
  for (int mi = 0; mi < 4; mi++)
    #pragma unroll
    for (int ni = 0; ni < 4; ni++)
      #pragma unroll
      for (int r = 0; r < 4; r++) {
        int m = m0 + wr * 64 + mi * 16 + quad * 4 + r;
        int n = n0 + wc * 64 + ni * 16 + l16;
        float v = acc[mi][ni][r] * scale;
        if (MODE == 0) {
          int b = m >> 11, s = m & 2047, hh = n >> 7, dh = n & 127;
          Cbf[(((size_t)(b * 8 + hh) * 2048 + s) << 7) + dh] = (bf16)v;
        } else {
          Cf32[(size_t)m * 1024 + n] = v;
        }
      }
}

// ---------------- flash attention (causal) ----------------
// R1: double-buffered K/V via global_load_lds DMA, counted vmcnt(8), raw s_barrier,
//     both-sides 16B-chunk XOR swizzle. R2: DPP row_ror softmax reductions.
// R3: perfect balance + full co-residency: grid (16,32); block x runs q-tiles (31-x)
//     then (x) = exactly 33 KV-iterations every block; 512 blocks = exactly 2/CU.
__global__ __launch_bounds__(256) void attn_kernel(const bf16* __restrict__ qb,
                                                   const bf16* __restrict__ kb,
                                                   const bf16* __restrict__ vbT,
                                                   bf16* __restrict__ outb) {
  const int bh = blockIdx.y;
  const int b = bh >> 3, h = bh & 7;
  __shared__ __align__(16) bf16 Ks[2][64 * 128];    // [buf][k-row * 128 + dh], swizzled
  __shared__ __align__(16) bf16 VTs[2][128 * 64];   // [buf][dh-row * 64 + s], swizzled
  __shared__ __align__(16) bf16 Ps[4][16][72];
  const int t = threadIdx.x, wave = t >> 6, lane = t & 63;
  const int quad = lane >> 4, l16 = lane & 15;
  const bf16* qbase  = qb  + (size_t)bh * 2048 * 128;
  const bf16* kbase  = kb  + (size_t)bh * 2048 * 128;
  const bf16* vtbase = vbT + (size_t)bh * 128 * 2048;

  auto stage = [&](int buf, int kt) {
    #pragma unroll
    for (int p = 0; p < 4; p++) {
      int o = p * 4096 + wave * 1024 + lane * 16;        // byte offset in 16 KiB tile
      int kr = o >> 8, kc = o & 255;                     // 256 B rows (128 bf16)
      async16((const char*)kbase + (size_t)(kt * 64 + kr) * 256 + (kc ^ ((kr & 7) << 4)),
              (char*)&Ks[buf][0] + o);
    }
    #pragma unroll
    for (int p = 0; p < 4; p++) {
      int o = p * 4096 + wave * 1024 + lane * 16;
      int vr = o >> 7, vc = o & 127;                     // 128 B rows (64 bf16)
      async16((const char*)vtbase + (size_t)vr * 4096 + kt * 128 + (vc ^ ((vr & 7) << 4)),
              (char*)&VTs[buf][0] + o);
    }
  };

  #pragma unroll 1
  for (int pass = 0; pass < 2; pass++) {
    const int qt = pass ? blockIdx.x : (31 - blockIdx.x);   // heavy tile first

    bf16x8 qf[4];
    #pragma unroll
    for (int dk = 0; dk < 4; dk++)
      qf[dk] = *(const bf16x8*)(qbase + (size_t)(qt * 64 + wave * 16 + l16) * 128 + dk * 32 + quad * 8);

    float m_run[4], l_run[4];
    fx4 acc_o[8] = {};
    #pragma unroll
    for (int r = 0; r < 4; r++) { m_run[r] = -1e30f; l_run[r] = 0.f; }

    stage(0, 0);
    int cur = 0;

    for (int kt = 0; kt <= qt; kt++) {
      if (kt < qt) {
        stage(cur ^ 1, kt + 1);                            // prefetch next tile
        asm volatile("s_waitcnt vmcnt(8)" ::: "memory");   // wait tile kt only
      } else {
        asm volatile("s_waitcnt vmcnt(0)" ::: "memory");
      }
      __builtin_amdgcn_s_barrier();
      asm volatile("" ::: "memory");

      const char* Ksb  = (const char*)&Ks[cur][0];
      const char* VTsb = (const char*)&VTs[cur][0];

      fx4 accs[4] = {};
      __builtin_amdgcn_s_setprio(1);
      #pragma unroll
      for (int ni = 0; ni < 4; ni++)
        #pragma unroll
        for (int dk = 0; dk < 4; dk++) {
          int r = ni * 16 + l16;
          bf16x8 kf = *(const bf16x8*)(Ksb + r * 256 + ((dk * 64 + quad * 16) ^ ((r & 7) << 4)));
          accs[ni] = __builtin_amdgcn_mfma_f32_16x16x32_bf16(qf[dk], kf, accs[ni], 0, 0, 0);
        }
      __builtin_amdgcn_s_setprio(0);

      if (kt == qt) {   // causal mask on the diagonal tile
        #pragma unroll
        for (int ni = 0; ni < 4; ni++)
          #pragma unroll
          for (int r = 0; r < 4; r++) {
            int qr = wave * 16 + quad * 4 + r;
            int kc = ni * 16 + l16;
            if (kc > qr) accs[ni][r] = -1e30f;
          }
      }

      // softmax in exp2 domain (log2e folded into Q scale); DPP row_ror reductions
      #pragma unroll
      for (int r = 0; r < 4; r++) {
        float mx = fmaxf(fmaxf(accs[0][r], accs[1][r]), fmaxf(accs[2][r], accs[3][r]));
        mx = fmaxf(mx, dppf<0x121>(mx));   // row_ror:1
        mx = fmaxf(mx, dppf<0x122>(mx));   // row_ror:2
        mx = fmaxf(mx, dppf<0x124>(mx));   // row_ror:4
        mx = fmaxf(mx, dppf<0x128>(mx));   // row_ror:8
        float m_new = fmaxf(m_run[r], mx);
        float alpha = __builtin_amdgcn_exp2f(m_run[r] - m_new);
        float rs = 0.f;
        #pragma unroll
        for (int ni = 0; ni < 4; ni++) {
          float p = __builtin_amdgcn_exp2f(accs[ni][r] - m_new);
          accs[ni][r] = p; rs += p;
        }
        rs += dppf<0x121>(rs);
        rs += dppf<0x122>(rs);
        rs += dppf<0x124>(rs);
        rs += dppf<0x128>(rs);
        l_run[r] = l_run[r] * alpha + rs;
        m_run[r] = m_new;
        #pragma unroll
        for (int nj = 0; nj < 8; nj++) acc_o[nj][r] *= alpha;
      }

      // P: C-layout -> LDS -> A-layout (per-wave region; DS in-order within a wave)
      #pragma unroll
      for (int ni = 0; ni < 4; ni++)
        #pragma unroll
        for (int r = 0; r < 4; r++)
          Ps[wave][quad * 4 + r][ni * 16 + l16] = (bf16)accs[ni][r];

      __builtin_amdgcn_s_setprio(1);
      #pragma unroll
      for (int step = 0; step < 2; step++) {
        bf16x8 pf = *(const bf16x8*)&Ps[wave][l16][step * 32 + quad * 8];
        #pragma unroll
        for (int nj = 0; nj < 8; nj++) {
          int r = nj * 16 + l16;
          bf16x8 vf = *(const bf16x8*)(VTsb + r * 128 + ((step * 64 + quad * 16) ^ ((r & 7) << 4)));
          acc_o[nj] = __builtin_amdgcn_mfma_f32_16x16x32_bf16(pf, vf, acc_o[nj], 0, 0, 0);
        }
      }
      __builtin_amdgcn_s_setprio(0);

      asm volatile("" ::: "memory");
      __builtin_amdgcn_s_barrier();   // all waves done reading buf[cur] before re-stage
      cur ^= 1;
    }

    #pragma unroll
    for (int nj = 0; nj < 8; nj++)
      #pragma unroll
      for (int r = 0; r < 4; r++) {
        int s = qt * 64 + wave * 16 + quad * 4 + r;
        int token = b * 2048 + s;
        float o = acc_o[nj][r] / l_run[r];
        outb[((size_t)token * 8 + h) * 128 + nj * 16 + l16] = (bf16)o;
      }
  }
}

// ---------------- launch ----------------
extern "C" void kernel_launch(void* const* d_in, const int* in_sizes, int n_in,
                              void* d_out, int out_size, void* d_ws, size_t ws_size,
                              hipStream_t stream) {
  const float* q_src  = (const float*)d_in[0];
  const float* k_src  = (const float*)d_in[1];
  const float* v_src  = (const float*)d_in[2];
  const float* wq     = (const float*)d_in[3];
  const float* wk     = (const float*)d_in[4];
  const float* sel_v_w = (const float*)d_in[5];
  const float* sel_o_w = (const float*)d_in[6];
  const float* v_w    = (const float*)d_in[7];
  const float* o_w    = (const float*)d_in[8];
  const float* bias_v = (const float*)d_in[9];
  const float* bias_o = (const float*)d_in[10];
  float* out = (float*)d_out;

  char* ws = (char*)d_ws;
  size_t off = 0;
  auto alloc = [&](size_t bytes) { char* p = ws + off; off += (bytes + 255) & ~(size_t)255; return p; };
  bf16* wqb   = (bf16*)alloc((size_t)1024 * 1024 * 2);
  bf16* wkb   = (bf16*)alloc((size_t)1024 * 1024 * 2);
  bf16* wvt   = (bf16*)alloc((size_t)8 * 128 * 4 * 1024 * 2);
  bf16* wot   = (bf16*)alloc((size_t)1024 * 4096 * 2);
  float* gate_v = (float*)alloc((size_t)8192 * 32 * 4);
  float* gate_o = (float*)alloc((size_t)8192 * 32 * 4);
  bf16* qsb   = (bf16*)alloc((size_t)8192 * 1024 * 2);   // bf16 copies of srcs
  bf16* ksb   = (bf16*)alloc((size_t)8192 * 1024 * 2);
  bf16* vsb   = (bf16*)alloc((size_t)8192 * 1024 * 2);
  bf16* qb    = (bf16*)alloc((size_t)8192 * 1024 * 2);   // [b,h,s,dh]
  bf16* kb    = (bf16*)alloc((size_t)8192 * 1024 * 2);   // [b,h,s,dh]
  bf16* vbT   = (bf16*)alloc((size_t)8192 * 1024 * 2);   // [b,h,dh,s]
  bf16* outb  = (bf16*)alloc((size_t)8192 * 1024 * 2);   // [b,s,h,dh]
  // Ae (8192x4096 bf16 = 64 MB) overlays qsb..qb, all dead by the time expand_o runs
  bf16* Ae    = qsb;

  f32_to_bf16<<<1024, 256, 0, stream>>>((const float4*)wq, (bf16x4*)wqb, 262144);
  f32_to_bf16<<<1024, 256, 0, stream>>>((const float4*)wk, (bf16x4*)wkb, 262144);
  f32_to_bf16<<<8192, 256, 0, stream>>>((const float4*)q_src, (bf16x4*)qsb, 2097152);
  f32_to_bf16<<<8192, 256, 0, stream>>>((const float4*)k_src, (bf16x4*)ksb, 2097152);
  f32_to_bf16<<<8192, 256, 0, stream>>>((const float4*)v_src, (bf16x4*)vsb, 2097152);
  make_wvt<<<dim3(16, 2, 32), 256, 0, stream>>>(v_w, wvt);
  make_wot<<<dim3(16, 2, 32), 256, 0, stream>>>(o_w, wot);
  gating<<<dim3(128, 2), 256, 0, stream>>>(q_src, k_src, sel_v_w, sel_o_w,
                                           bias_v, bias_o, gate_v, gate_o, out);

  const float ssq = 0.29730177875068026f;            // 128^-0.25 (applied to both q and k)
  const float log2e = 1.4426950408889634f;
  gemm_moe<0><<<256, 512, 0, stream>>>(qsb, wqb, nullptr, qb, nullptr, ssq * log2e);
  gemm_moe<0><<<256, 512, 0, stream>>>(ksb, wkb, nullptr, kb, nullptr, ssq);
  gemm_moe<1><<<256, 512, 0, stream>>>(vsb, wvt, gate_v, vbT, nullptr, 1.0f);
  attn_kernel<<<dim3(16, 32), 256, 0, stream>>>(qb, kb, vbT, outb);
  expand_o<<<16384, 256, 0, stream>>>(outb, gate_o, Ae);
  gemm_moe<2><<<256, 512, 0, stream>>>(Ae, wot, nullptr, nullptr, out, 1.0f);
}